// Round 1
// 673.075 us; speedup vs baseline: 1.1423x; 1.1423x over previous
//
#include <hip/hip_runtime.h>
#include <hip/hip_bf16.h>

// Problem constants (BlockInvariantPointAttention):
// B=2 N=2048 BQ=32 BK=128 NB=64 CS=384 CZ=128 CH=16 H=12 PQK=4 PV=8
// feats per row: o(192) | o_pt_f(288) | o_pt_d(96) | o_pair(384) = 960
// All float inputs/outputs are FLOAT32; key_idx int32.
// Attention path: MFMA head-pair blocks; logits contraction = [16 qk | 12 pt | 4 pad]
//   with scales folded into Kext (0.1443 on qk part, -2*hwe_h on pt part).

typedef unsigned int uint_t;
typedef unsigned short ushort_t;
__device__ __forceinline__ float b2f(const __hip_bfloat16 x) { return __bfloat162float(x); }
__device__ __forceinline__ __hip_bfloat16 f2b(float x) { return __float2bfloat16(x); }
__device__ __forceinline__ ushort_t f2bu(float x) {
  __hip_bfloat16 h = __float2bfloat16(x);
  return *(ushort_t*)&h;
}
__device__ __forceinline__ float b2fu(ushort_t u) {
  union { uint_t i; float f; } c; c.i = ((uint_t)u) << 16; return c.f;
}
__device__ __forceinline__ uint_t pack2(float a, float b) {
  return (uint_t)f2bu(a) | ((uint_t)f2bu(b) << 16);
}
typedef __attribute__((ext_vector_type(8))) short short8x;   // 8 bf16 (4 VGPRs)
typedef __attribute__((ext_vector_type(4))) float floatx4;   // MFMA accumulator

// ---------------------------------------------------------------------------
// K0: LayerNorm of s -> sN.  Block 512 (extra) precomputes the block-invariant
// z-path weight tile Wt (bf16, [48][128]) plus uu[48]/vv[48] correction terms
// so k_z doesn't rebuild them 8192 times (that rebuild was a 44-way-bank-
// conflicted serial loop + redundant global reads).
// ---------------------------------------------------------------------------
__global__ __launch_bounds__(256) void k_ln(
    const float* __restrict__ s, const float* __restrict__ g_s,
    const float* __restrict__ b_s, float* __restrict__ sN,
    const float* __restrict__ g_z, const float* __restrict__ b_z,
    const float* __restrict__ Wb, const float* __restrict__ Wdz,
    ushort_t* __restrict__ Wt_g, float* __restrict__ uv_g)
{
  if (blockIdx.x >= 512) {
    // --- weight prep block ---
    const int tid = threadIdx.x;
    for (int e = tid; e < 48 * 128; e += 256) {
      int c = e >> 7, k = e & 127;
      float v = 0.f;
      if (c < 12)      v = g_z[k] * Wb[k * 12 + c];
      else if (c < 44) v = g_z[k] * Wdz[k * 32 + (c - 12)];
      Wt_g[e] = f2bu(v);
    }
    int c = tid >> 2, p = tid & 3;
    float us_ = 0.f, vs_ = 0.f;
    if (c < 44) {
      for (int k = p * 32; k < p * 32 + 32; k++) {
        float worig = (c < 12) ? Wb[k * 12 + c] : Wdz[k * 32 + (c - 12)];
        us_ += b2fu(f2bu(g_z[k] * worig));   // matches bf16-rounded MFMA weights
        vs_ += b_z[k] * worig;
      }
    }
    us_ += __shfl_xor(us_, 1, 64); us_ += __shfl_xor(us_, 2, 64);
    vs_ += __shfl_xor(vs_, 1, 64); vs_ += __shfl_xor(vs_, 2, 64);
    if (p == 0 && c < 48) { uv_g[c] = us_; uv_g[48 + c] = vs_; }
    return;
  }
  const int tid = threadIdx.x;
  const int w = tid >> 6, l = tid & 63;
  #pragma unroll
  for (int ii = 0; ii < 2; ii++) {
    int row = blockIdx.x * 8 + w * 2 + ii;
    const float* sr = s + (size_t)row * 384;
    float x[6], s1 = 0.f, s2 = 0.f;
    #pragma unroll
    for (int j = 0; j < 6; j++) { x[j] = sr[l + j * 64]; s1 += x[j]; s2 += x[j] * x[j]; }
    #pragma unroll
    for (int m = 1; m < 64; m <<= 1) { s1 += __shfl_xor(s1, m, 64); s2 += __shfl_xor(s2, m, 64); }
    float mean = s1 * (1.f / 384.f);
    float var = s2 * (1.f / 384.f) - mean * mean;
    float rstd = rsqrtf(var + 1e-5f);
    float* dr = sN + (size_t)row * 384;
    #pragma unroll
    for (int j = 0; j < 6; j++) {
      int c = l + j * 64;
      dr[c] = (x[j] - mean) * rstd * g_s[c] + b_s[c];
    }
  }
}

// ---------------------------------------------------------------------------
// K1: proj = sN(4096x384) @ Wcat(384x1152).  BM=32 BN=128 BK=16.
// ---------------------------------------------------------------------------
__global__ __launch_bounds__(256) void k_pgemm(
    const float* __restrict__ sN,
    const float* __restrict__ Wq, const float* __restrict__ Wk,
    const float* __restrict__ Wv, const float* __restrict__ Wqp,
    const float* __restrict__ Wkvp,
    float* __restrict__ proj)
{
  __shared__ __align__(16) float sA[16][32];
  __shared__ __align__(16) float sB[16][128];
  const int tid = threadIdx.x;
  const int mt = blockIdx.x & 127;
  const int nt = blockIdx.x >> 7;
  const int m0 = mt * 32, n0 = nt * 128;
  const int tm = tid >> 5, tn = tid & 31;

  const float* bsrc[2]; int bstride[2]; int bk[2];
  #pragma unroll
  for (int u = 0; u < 2; u++) {
    int idx = tid + u * 256;
    int k = idx >> 5, n4 = idx & 31;
    int col0 = n0 + n4 * 4;
    const float* p; int st;
    if (col0 < 192)      { p = Wq   + col0;         st = 192; }
    else if (col0 < 384) { p = Wk   + (col0 - 192); st = 192; }
    else if (col0 < 576) { p = Wv   + (col0 - 384); st = 192; }
    else if (col0 < 720) { p = Wqp  + (col0 - 576); st = 144; }
    else                 { p = Wkvp + (col0 - 720); st = 432; }
    bsrc[u] = p; bstride[u] = st; bk[u] = k;
  }
  const int am = tid >> 2, ak4 = tid & 3;

  float acc[4][4];
  #pragma unroll
  for (int i = 0; i < 4; i++)
    #pragma unroll
    for (int j = 0; j < 4; j++) acc[i][j] = 0.f;

  for (int k0 = 0; k0 < 384; k0 += 16) {
    #pragma unroll
    for (int u = 0; u < 2; u++) {
      float4 wv4 = *(const float4*)(bsrc[u] + (size_t)(k0 + bk[u]) * bstride[u]);
      *(float4*)&sB[bk[u]][(tid + u * 256 & 31) * 4] = wv4;
    }
    if (tid < 128) {
      float4 a4 = *(const float4*)(sN + (size_t)(m0 + am) * 384 + k0 + ak4 * 4);
      sA[ak4 * 4 + 0][am] = a4.x;
      sA[ak4 * 4 + 1][am] = a4.y;
      sA[ak4 * 4 + 2][am] = a4.z;
      sA[ak4 * 4 + 3][am] = a4.w;
    }
    __syncthreads();
    #pragma unroll
    for (int kk = 0; kk < 16; kk++) {
      float4 a4 = *(const float4*)&sA[kk][tm * 4];
      float4 b4 = *(const float4*)&sB[kk][tn * 4];
      const float* av = (const float*)&a4;
      const float* bv = (const float*)&b4;
      #pragma unroll
      for (int i = 0; i < 4; i++)
        #pragma unroll
        for (int j = 0; j < 4; j++) acc[i][j] += av[i] * bv[j];
    }
    __syncthreads();
  }
  #pragma unroll
  for (int i = 0; i < 4; i++)
    *(float4*)(proj + (size_t)(m0 + tm * 4 + i) * 1152 + n0 + tn * 4) = *(float4*)&acc[i][0];
}

// ---------------------------------------------------------------------------
// K2: rotations + point norms + scatter to pos* buffers. 8 positions/block.
// ---------------------------------------------------------------------------
__global__ __launch_bounds__(256) void k_rot(
    const float* __restrict__ proj_g,
    const float* __restrict__ trans, const float* __restrict__ rots,
    float* __restrict__ posq, float* __restrict__ posk, float* __restrict__ posv,
    float* __restrict__ posqp, float* __restrict__ poskp, float* __restrict__ posvp,
    float* __restrict__ posqn, float* __restrict__ poskn)
{
  __shared__ __align__(16) float proj[8][1152];
  __shared__ float rt[8][12];
  const int tid = threadIdx.x;
  const int p0 = blockIdx.x * 8;

  for (int e = tid; e < 8 * 288; e += 256)
    ((float4*)&proj[0][0])[e] = ((const float4*)(proj_g + (size_t)p0 * 1152))[e];
  for (int e = tid; e < 8 * 12; e += 256) {
    int i = e / 12, c = e % 12;
    rt[i][c] = (c < 9) ? rots[(size_t)(p0 + i) * 9 + c]
                       : trans[(size_t)(p0 + i) * 3 + (c - 9)];
  }
  __syncthreads();

  for (int e = tid; e < 8 * 192; e += 256) {
    int i = e / 192, p = e % 192;
    float R0 = rt[i][0], R1 = rt[i][1], R2 = rt[i][2];
    float R3 = rt[i][3], R4 = rt[i][4], R5 = rt[i][5];
    float R6 = rt[i][6], R7 = rt[i][7], R8 = rt[i][8];
    float tx = rt[i][9], ty = rt[i][10], tz = rt[i][11];
    size_t pos = p0 + i;
    if (p < 48) {
      int base = 576 + p * 3;
      float v0 = proj[i][base], v1 = proj[i][base + 1], v2 = proj[i][base + 2];
      float o0 = R0 * v0 + R1 * v1 + R2 * v2 + tx;
      float o1 = R3 * v0 + R4 * v1 + R5 * v2 + ty;
      float o2 = R6 * v0 + R7 * v1 + R8 * v2 + tz;
      proj[i][base] = o0; proj[i][base + 1] = o1; proj[i][base + 2] = o2;
      posqp[pos * 144 + p * 3 + 0] = o0;
      posqp[pos * 144 + p * 3 + 1] = o1;
      posqp[pos * 144 + p * 3 + 2] = o2;
    } else {
      int p2 = p - 48;
      int base = 720 + p2 * 3;
      float v0 = proj[i][base], v1 = proj[i][base + 1], v2 = proj[i][base + 2];
      float o0 = R0 * v0 + R1 * v1 + R2 * v2 + tx;
      float o1 = R3 * v0 + R4 * v1 + R5 * v2 + ty;
      float o2 = R6 * v0 + R7 * v1 + R8 * v2 + tz;
      int h = p2 / 12, idx = p2 % 12;
      if (idx < 4) {
        proj[i][base] = o0; proj[i][base + 1] = o1; proj[i][base + 2] = o2;
        poskp[pos * 144 + h * 12 + idx * 3 + 0] = o0;
        poskp[pos * 144 + h * 12 + idx * 3 + 1] = o1;
        poskp[pos * 144 + h * 12 + idx * 3 + 2] = o2;
      } else {
        posvp[pos * 288 + h * 24 + (idx - 4) * 3 + 0] = o0;
        posvp[pos * 288 + h * 24 + (idx - 4) * 3 + 1] = o1;
        posvp[pos * 288 + h * 24 + (idx - 4) * 3 + 2] = o2;
      }
    }
  }
  __syncthreads();

  for (int e = tid; e < 96; e += 256) {
    int i = e / 12, h = e % 12;
    size_t pos = p0 + i;
    float qs = 0.f, ks = 0.f;
    #pragma unroll
    for (int u = 0; u < 12; u++) {
      float a_ = proj[i][576 + h * 12 + u];
      qs += a_ * a_;
      float c_ = proj[i][720 + h * 36 + u];
      ks += c_ * c_;
    }
    posqn[pos * 12 + h] = qs;
    poskn[pos * 12 + h] = ks;
  }
  for (int e = tid; e < 8 * 576; e += 256) {
    int i = e / 576, c = e % 576;
    size_t pos = p0 + i;
    float v = proj[i][c];
    if (c < 192)      posq[pos * 192 + c]         = v;
    else if (c < 384) posk[pos * 192 + (c - 192)] = v;
    else              posv[pos * 192 + (c - 384)] = v;
  }
}

// ---------------------------------------------------------------------------
// K3: z path, single-pass MFMA. 64 pair-rows/block, 8192 blocks.
// Redesigned: NO LDS, NO barriers. A-fragments of raw z loaded directly from
// global in fragment order (the 4 quad-lanes sharing r16 collectively cover
// the full 128-col row, so LN row stats come from 2 xor-shuffles).  B-frags
// come from the precomputed global Wt tile (L2-broadcast).  LN applied as
// post-MFMA affine correction with precomputed uu/vv.
// Outputs: bbias_t [(b*64+nb)*12+h][q*128+k] bf16 (packed 8B stores)
//          pzt    [(b*64+nb)*32+q][c(32)][k(128)] bf16 (transposed pair_z)
// ---------------------------------------------------------------------------
__global__ __launch_bounds__(256) void k_z(
    const float* __restrict__ z,
    const ushort_t* __restrict__ Wt_g, const float* __restrict__ uv_g,
    ushort_t* __restrict__ bbias_t, ushort_t* __restrict__ pzt)
{
  const int tid = threadIdx.x;
  const int w = tid >> 6, lane = tid & 63, quad = lane >> 4, r16 = lane & 15;
  const size_t row0 = (size_t)blockIdx.x * 64;
  const int lrow = w * 16 + r16;                 // this lane's A row (0..63)
  const float* zr = z + (row0 + lrow) * 128;

  // B fragments (loop-invariant), from global Wt tile: rows 44..47 are zeros.
  short8x bf[3][4];
  #pragma unroll
  for (int nt = 0; nt < 3; nt++)
    #pragma unroll
    for (int kk = 0; kk < 4; kk++)
      bf[nt][kk] = *(const short8x*)(Wt_g + (size_t)(nt * 16 + r16) * 128 + kk * 32 + quad * 8);

  // A fragments: 32 raw z floats per lane, cols {quad*8 + kk*32 .. +7}.
  union { short8x v; uint_t u[4]; } afu[4];
  float s1 = 0.f, s2 = 0.f;
  #pragma unroll
  for (int kk = 0; kk < 4; kk++) {
    float4 a = *(const float4*)(zr + kk * 32 + quad * 8);
    float4 b = *(const float4*)(zr + kk * 32 + quad * 8 + 4);
    s1 += a.x + a.y + a.z + a.w + b.x + b.y + b.z + b.w;
    s2 += a.x * a.x + a.y * a.y + a.z * a.z + a.w * a.w
        + b.x * b.x + b.y * b.y + b.z * b.z + b.w * b.w;
    afu[kk].u[0] = pack2(a.x, a.y);
    afu[kk].u[1] = pack2(a.z, a.w);
    afu[kk].u[2] = pack2(b.x, b.y);
    afu[kk].u[3] = pack2(b.z, b.w);
  }
  // Row stats: combine the 4 quad-lanes that share r16 (xor 16, 32).
  s1 += __shfl_xor(s1, 16, 64); s1 += __shfl_xor(s1, 32, 64);
  s2 += __shfl_xor(s2, 16, 64); s2 += __shfl_xor(s2, 32, 64);
  float mean = s1 * (1.f / 128.f);
  float rstd = rsqrtf(s2 * (1.f / 128.f) - mean * mean + 1e-5f);

  floatx4 acc[3] = { {0,0,0,0}, {0,0,0,0}, {0,0,0,0} };
  #pragma unroll
  for (int kk = 0; kk < 4; kk++)
    #pragma unroll
    for (int nt = 0; nt < 3; nt++)
      acc[nt] = __builtin_amdgcn_mfma_f32_16x16x32_bf16(afu[kk].v, bf[nt][kk], acc[nt], 0, 0, 0);

  // C layout: row = quad*4+reg, col = r16.  Fetch stats for output rows
  // w*16 + quad*4 + reg from the lane that owns that row (lane id = row&15).
  float mr[4], rr[4];
  #pragma unroll
  for (int reg = 0; reg < 4; reg++) {
    int src = quad * 4 + reg;
    mr[reg] = __shfl(mean, src, 64);
    rr[reg] = __shfl(rstd, src, 64);
  }

  const int bp = (int)(blockIdx.x >> 6);           // = b*64+nb
  const int qk0 = ((int)blockIdx.x & 63) * 64;     // local (q*128+k) base
  const int qloc = qk0 >> 7;                       // q index 0..31
  const int kbase = (qk0 & 127) + w * 16 + quad * 4;
  #pragma unroll
  for (int nt = 0; nt < 3; nt++) {
    int c = nt * 16 + r16;
    if (c < 44) {
      float uc = uv_g[c], vc = uv_g[48 + c];
      float vals[4];
      #pragma unroll
      for (int reg = 0; reg < 4; reg++)
        vals[reg] = rr[reg] * acc[nt][reg] - mr[reg] * rr[reg] * uc + vc;
      uint2 pk = make_uint2(pack2(vals[0], vals[1]), pack2(vals[2], vals[3]));
      if (c < 12) {
        size_t el = (((size_t)(bp * 12 + c)) << 12) + qk0 + w * 16 + quad * 4;
        *(uint2*)(bbias_t + el) = pk;
      } else {
        size_t el = (((size_t)((bp * 32 + qloc) * 32 + (c - 12))) << 7) + kbase;
        *(uint2*)(pzt + el) = pk;
      }
    }
  }
}

// ---------------------------------------------------------------------------
// K4: attention. 768 blocks = (b, nb, head-pair). 4 waves = (head, q-half).
// Per wave: 8 logits MFMA -> in-register softmax -> 12 PV MFMA -> epilogues.
// ---------------------------------------------------------------------------
__global__ __launch_bounds__(256) void k_attn(
    const float* __restrict__ posq, const float* __restrict__ posk,
    const float* __restrict__ posv, const float* __restrict__ posqp,
    const float* __restrict__ poskp, const float* __restrict__ posvp,
    const float* __restrict__ posqn, const float* __restrict__ poskn,
    const ushort_t* __restrict__ bbias_t,
    const float* __restrict__ s_mask, const int* __restrict__ key_idx,
    const float* __restrict__ trans, const float* __restrict__ rots,
    const float* __restrict__ head_w,
    float* __restrict__ feats, ushort_t* __restrict__ P_ws)
{
  __shared__ __align__(16) ushort_t sK[2 * 128 * 40];  // Kext [hh][k][40] (use 0..31)
  __shared__ __align__(16) ushort_t sV[2 * 48 * 136];  // Vext [hh][c][136] (k 0..127)
  __shared__ __align__(16) ushort_t sQ[2 * 32 * 40];   // Qext [hh][q][40]
  __shared__ __align__(16) ushort_t sP[64 * 136];      // P    [w*16+row][136]
  __shared__ float sOpt[64 * 25];                      // o_pt raw [w*16+row][25]
  __shared__ float rt[32][12];
  __shared__ float kn_l[2][128];
  __shared__ float qn_l[2][32];
  __shared__ float kmask[128];
  __shared__ float qmask[32];
  __shared__ int   kidx[128];
  __shared__ float hwe2[2];

  const int tid = threadIdx.x;
  const int bid = blockIdx.x;
  const int b = bid / 384;
  const int rem = bid % 384;
  const int nb = rem / 6;
  const int hp = rem % 6;
  const int h0 = hp * 2;
  const int rowbase = b * 2048 + nb * 32;

  if (tid < 128) kidx[tid] = key_idx[nb * 128 + tid];
  if (tid < 2) hwe2[tid] = -0.5f * 0.13608276348795434f * log1pf(expf(head_w[h0 + tid]));
  __syncthreads();

  if (tid < 128) kmask[tid] = s_mask[b * 2048 + kidx[tid]];
  if (tid < 32) qmask[tid] = s_mask[rowbase + tid];
  for (int e = tid; e < 384; e += 256) {
    int i = e / 12, c = e % 12;
    rt[i][c] = (c < 9) ? rots[(size_t)(rowbase + i) * 9 + c]
                       : trans[(size_t)(rowbase + i) * 3 + (c - 9)];
  }

  // ---- Kext + kn staging: thread <-> (hh, k) ----
  {
    int hh = tid >> 7, k = tid & 127, h = h0 + hh;
    int gk = b * 2048 + kidx[k];
    kn_l[hh][k] = poskn[(size_t)gk * 12 + h];
    float sq = 0.14433756729740643f;
    float sp = -2.f * hwe2[hh];
    const float* kr = posk + (size_t)gk * 192 + h * 16;
    #pragma unroll
    for (int c4 = 0; c4 < 4; c4++) {
      float4 v4 = *(const float4*)(kr + c4 * 4);
      uint2 pk = make_uint2(pack2(sq * v4.x, sq * v4.y), pack2(sq * v4.z, sq * v4.w));
      *(uint2*)&sK[(hh * 128 + k) * 40 + c4 * 4] = pk;
    }
    const float* kpr = poskp + (size_t)gk * 144 + h * 12;
    #pragma unroll
    for (int c4 = 0; c4 < 3; c4++) {
      float4 v4 = *(const float4*)(kpr + c4 * 4);
      uint2 pk = make_uint2(pack2(sp * v4.x, sp * v4.y), pack2(sp * v4.z, sp * v4.w));
      *(uint2*)&sK[(hh * 128 + k) * 40 + 16 + c4 * 4] = pk;
    }
    *(uint2*)&sK[(hh * 128 + k) * 40 + 28] = make_uint2(0u, 0u);
  }
  // ---- Vext staging (transposed, k-pairs packed): thread <-> (hh, k-pair, c-half) ----
  {
    int hh = tid >> 7, t7 = tid & 127, h = h0 + hh;
    int k2 = t7 >> 1, cg = t7 & 1, kk0 = k2 * 2;
    int ga = b * 2048 + kidx[kk0], gb = b * 2048 + kidx[kk0 + 1];
    if (cg == 0) {
      const float* A_ = posv + (size_t)ga * 192 + h * 16;
      const float* B_ = posv + (size_t)gb * 192 + h * 16;
      #pragma unroll
      for (int c4 = 0; c4 < 4; c4++) {
        float4 a4 = *(const float4*)(A_ + c4 * 4);
        float4 b4 = *(const float4*)(B_ + c4 * 4);
        #pragma unroll
        for (int j = 0; j < 4; j++)
          *(uint_t*)&sV[(hh * 48 + c4 * 4 + j) * 136 + kk0] =
              pack2(((const float*)&a4)[j], ((const float*)&b4)[j]);
      }
    } else {
      const float* A_ = posvp + (size_t)ga * 288 + h * 24;
      const float* B_ = posvp + (size_t)gb * 288 + h * 24;
      #pragma unroll
      for (int c4 = 0; c4 < 6; c4++) {
        float4 a4 = *(const float4*)(A_ + c4 * 4);
        float4 b4 = *(const float4*)(B_ + c4 * 4);
        #pragma unroll
        for (int j = 0; j < 4; j++)
          *(uint_t*)&sV[(hh * 48 + 16 + c4 * 4 + j) * 136 + kk0] =
              pack2(((const float*)&a4)[j], ((const float*)&b4)[j]);
      }
      #pragma unroll
      for (int j = 0; j < 8; j++)
        *(uint_t*)&sV[(hh * 48 + 40 + j) * 136 + kk0] = 0u;
    }
  }
  // ---- Qext + qn staging: thread <-> (hh, q), tid<64 ----
  if (tid < 64) {
    int hh = tid >> 5, q = tid & 31, h = h0 + hh;
    qn_l[hh][q] = posqn[(size_t)(rowbase + q) * 12 + h];
    const float* qr = posq + (size_t)(rowbase + q) * 192 + h * 16;
    #pragma unroll
    for (int c4 = 0; c4 < 4; c4++) {
      float4 v4 = *(const float4*)(qr + c4 * 4);
      uint2 pk = make_uint2(pack2(v4.x, v4.y), pack2(v4.z, v4.w));
      *(uint2*)&sQ[(hh * 32 + q) * 40 + c4 * 4] = pk;
    }
    const float* qpr = posqp + (size_t)(rowbase + q) * 144 + h * 12;
    #pragma unroll
    for (int c4 = 0; c4 < 3; c4++) {
      float4 v4 = *(const float4*)(qpr + c4 * 4);
      uint2 pk = make_uint2(pack2(v4.x, v4.y), pack2(v4.z, v4.w));
      *(uint2*)&sQ[(hh * 32 + q) * 40 + 16 + c4 * 4] = pk;
    }
    *(uint2*)&sQ[(hh * 32 + q) * 40 + 28] = make_uint2(0u, 0u);
  }
  __syncthreads();

  // ---- per-wave compute ----
  const int w = tid >> 6, lane = tid & 63, quad = lane >> 4, r16 = lane & 15;
  const int hh = w >> 1, q0 = (w & 1) * 16;
  const int h = h0 + hh;
  const float hwe = hwe2[hh];

  short8x af = *(const short8x*)&sQ[(hh * 32 + q0 + r16) * 40 + quad * 8];
  floatx4 acc[8];
  #pragma unroll
  for (int nt = 0; nt < 8; nt++) {
    floatx4 z4 = {0.f, 0.f, 0.f, 0.f};
    short8x bf = *(const short8x*)&sK[(hh * 128 + nt * 16 + r16) * 40 + quad * 8];
    acc[nt] = __builtin_amdgcn_mfma_f32_16x16x32_bf16(af, bf, z4, 0, 0, 0);
  }

  const ushort_t* bb = bbias_t + (((size_t)((b * 64 + nb) * 12 + h)) << 12);
  float lg[8][4];
  #pragma unroll
  for (int nt = 0; nt < 8; nt++)
    #pragma unroll
    for (int reg = 0; reg < 4; reg++) {
      int qa = q0 + quad * 4 + reg;
      lg[nt][reg] = b2fu(bb[qa * 128 + nt * 16 + r16]);
    }
  float qnv[4], qmv[4];
  #pragma unroll
  for (int reg = 0; reg < 4; reg++) {
    int qa = q0 + quad * 4 + reg;
    qnv[reg] = qn_l[hh][qa]; qmv[reg] = qmask[qa];
  }
  #pragma unroll
  for (int nt = 0; nt < 8; nt++) {
    int col = nt * 16 + r16;
    float knv = kn_l[hh][col], kmv = kmask[col];
    #pragma unroll
    for (int reg = 0; reg < 4; reg++)
      lg[nt][reg] = acc[nt][reg] + 0.5773502691896258f * lg[nt][reg]
                  + hwe * (qnv[reg] + knv) + 100000.f * (qmv[reg] * kmv - 1.f);
  }
  // softmax over 128 keys per row (in-lane over nt, xor-shuffle over r16)
  float mx[4], sm[4];
  #pragma unroll
  for (int reg = 0; reg < 4; reg++) {
    float m = lg[0][reg];
    #pragma unroll
    for (int nt = 1; nt < 8; nt++) m = fmaxf(m, lg[nt][reg]);
    #pragma unroll
    for (int d = 1; d < 16; d <<= 1) m = fmaxf(m, __shfl_xor(m, d, 64));
    mx[reg] = m; sm[reg] = 0.f;
  }
  #pragma unroll
  for (int nt = 0; nt < 8; nt++)
    #pragma unroll
    for (int reg = 0; reg < 4; reg++) {
      float e = __expf(lg[nt][reg] - mx[reg]);
      lg[nt][reg] = e; sm[reg] += e;
    }
  #pragma unroll
  for (int reg = 0; reg < 4; reg++) {
    float s = sm[reg];
    #pragma unroll
    for (int d = 1; d < 16; d <<= 1) s += __shfl_xor(s, d, 64);
    sm[reg] = 1.f / s;
  }
  // P -> LDS (wave-private)
  #pragma unroll
  for (int nt = 0; nt < 8; nt++)
    #pragma unroll
    for (int reg = 0; reg < 4; reg++) {
      int row = quad * 4 + reg;
      sP[(w * 16 + row) * 136 + nt * 16 + r16] = f2bu(lg[nt][reg] * sm[reg]);
    }
  // PV
  short8x afp[4];
  #pragma unroll
  for (int kk = 0; kk < 4; kk++)
    afp[kk] = *(const short8x*)&sP[(w * 16 + r16) * 136 + kk * 32 + quad * 8];
  floatx4 o0 = {0.f,0.f,0.f,0.f}, o1 = {0.f,0.f,0.f,0.f}, o2 = {0.f,0.f,0.f,0.f};
  #pragma unroll
  for (int kk = 0; kk < 4; kk++) {
    short8x bv0 = *(const short8x*)&sV[(hh * 48 +  0 + r16) * 136 + kk * 32 + quad * 8];
    short8x bv1 = *(const short8x*)&sV[(hh * 48 + 16 + r16) * 136 + kk * 32 + quad * 8];
    short8x bv2 = *(const short8x*)&sV[(hh * 48 + 32 + r16) * 136 + kk * 32 + quad * 8];
    o0 = __builtin_amdgcn_mfma_f32_16x16x32_bf16(afp[kk], bv0, o0, 0, 0, 0);
    o1 = __builtin_amdgcn_mfma_f32_16x16x32_bf16(afp[kk], bv1, o1, 0, 0, 0);
    o2 = __builtin_amdgcn_mfma_f32_16x16x32_bf16(afp[kk], bv2, o2, 0, 0, 0);
  }
  // o epilogue (cols 0..15 = c)
  #pragma unroll
  for (int reg = 0; reg < 4; reg++) {
    int qa = q0 + quad * 4 + reg;
    feats[(size_t)(rowbase + qa) * 960 + h * 16 + r16] = o0[reg];
  }
  // o_pt raw -> LDS
  #pragma unroll
  for (int reg = 0; reg < 4; reg++) {
    int row = quad * 4 + reg;
    sOpt[(w * 16 + row) * 25 + r16] = o1[reg];
    if (r16 < 8) sOpt[(w * 16 + row) * 25 + 16 + r16] = o2[reg];
  }
  // rotation + norm epilogue (same wave; LDS deps via waitcnt)
  for (int e2 = lane; e2 < 128; e2 += 64) {
    int ql = e2 >> 3, v = e2 & 7;
    int qa = q0 + ql;
    float u0 = sOpt[(w * 16 + ql) * 25 + v * 3 + 0] - rt[qa][9];
    float u1 = sOpt[(w * 16 + ql) * 25 + v * 3 + 1] - rt[qa][10];
    float u2 = sOpt[(w * 16 + ql) * 25 + v * 3 + 2] - rt[qa][11];
    float w0 = rt[qa][0] * u0 + rt[qa][3] * u1 + rt[qa][6] * u2;
    float w1 = rt[qa][1] * u0 + rt[qa][4] * u1 + rt[qa][7] * u2;
    float w2 = rt[qa][2] * u0 + rt[qa][5] * u1 + rt[qa][8] * u2;
    size_t fb = (size_t)(rowbase + qa) * 960;
    feats[fb + 192 + h * 24 + v * 3 + 0] = w0;
    feats[fb + 192 + h * 24 + v * 3 + 1] = w1;
    feats[fb + 192 + h * 24 + v * 3 + 2] = w2;
    feats[fb + 480 + h * 8 + v] = sqrtf(w0 * w0 + w1 * w1 + w2 * w2 + 1e-8f);
  }
  // P -> global (for k_opair), coalesced uint stores
  {
    uint_t* Pg = (uint_t*)P_ws;
    size_t pb2 = (((size_t)((b * 64 + nb) * 12 + h)) << 12) >> 1;  // uint index base
    #pragma unroll
    for (int ql = 0; ql < 16; ql++) {
      uint_t pv = *(const uint_t*)&sP[(w * 16 + ql) * 136 + 2 * lane];
      Pg[pb2 + (size_t)(q0 + ql) * 64 + lane] = pv;
    }
  }
}

// ---------------------------------------------------------------------------
// K5: o_pair. 1024 blocks = (b, nb, q-quad). wave <-> q.
// A = P [m=h(pad16)][k=key] from global; B = pzt [n=c][k=key] via LDS.
// ---------------------------------------------------------------------------
__global__ __launch_bounds__(256) void k_opair(
    const ushort_t* __restrict__ P_ws, const ushort_t* __restrict__ pzt,
    float* __restrict__ feats)
{
  __shared__ __align__(16) ushort_t pzl[4 * 32 * 136];
  const int tid = threadIdx.x;
  const int w = tid >> 6, lane = tid & 63, quad = lane >> 4, r16 = lane & 15;
  const int bid = blockIdx.x;
  const int b = bid >> 9, rem = bid & 511, nb = rem >> 3, qg = rem & 7;
  const int q = qg * 4 + w;
  const int rowbase = b * 2048 + nb * 32;

  // stage this wave's pz tile (transposed layout already): 32 c-rows x 128 k
  const uint_t* src = (const uint_t*)pzt + ((((size_t)((b * 64 + nb) * 32 + q)) << 12) >> 1);
  #pragma unroll
  for (int c = 0; c < 32; c++) {
    uint_t v = src[c * 64 + lane];
    *(uint_t*)&pzl[(w * 32 + c) * 136 + 2 * lane] = v;
  }
  // A-frags from global P
  const ushort_t* Pp = P_ws + ((size_t)(b * 64 + nb) * 12) * 4096
                            + (size_t)r16 * 4096 + (size_t)q * 128;
  short8x af[4];
  #pragma unroll
  for (int kk = 0; kk < 4; kk++)
    af[kk] = *(const short8x*)(Pp + kk * 32 + quad * 8);

  floatx4 acc[2] = { {0.f,0.f,0.f,0.f}, {0.f,0.f,0.f,0.f} };
  #pragma unroll
  for (int kk = 0; kk < 4; kk++) {
    #pragma unroll
    for (int nt = 0; nt < 2; nt++) {
      short8x bf = *(const short8x*)&pzl[(w * 32 + nt * 16 + r16) * 136 + kk * 32 + quad * 8];
      acc[nt] = __builtin_amdgcn_mfma_f32_16x16x32_bf16(af[kk], bf, acc[nt], 0, 0, 0);
    }
  }
  #pragma unroll
  for (int nt = 0; nt < 2; nt++)
    #pragma unroll
    for (int reg = 0; reg < 4; reg++) {
      int hrow = quad * 4 + reg;
      if (hrow < 12)
        feats[(size_t)(rowbase + q) * 960 + 576 + hrow * 32 + nt * 16 + r16] = acc[nt][reg];
    }
}

// ---------------------------------------------------------------------------
// K6: out = feats(4096x960) @ Wout(960x384). 16 rows per block.
// ---------------------------------------------------------------------------
__global__ __launch_bounds__(256) void k_out(
    const float* __restrict__ feats, const float* __restrict__ Wout,
    float* __restrict__ out)
{
  __shared__ __align__(16) float frow[16][960];
  const int tid = threadIdx.x;
  const int p0 = blockIdx.x * 16;
  for (int e = tid; e < 16 * 240; e += 256) {
    int i = e / 240, cc = e % 240;
    ((float4*)&frow[i][0])[cc] = ((const float4*)&feats[(size_t)(p0 + i) * 960])[cc];
  }
  __syncthreads();
  const int w = tid >> 6, l = tid & 63;
  const int c0 = l * 6;
  float acc[4][6];
  #pragma unroll
  for (int i = 0; i < 4; i++)
    #pragma unroll
    for (int j = 0; j < 6; j++) acc[i][j] = 0.f;

  for (int ch = 0; ch < 240; ch++) {
    float4 f4[4];
    #pragma unroll
    for (int i = 0; i < 4; i++) f4[i] = *(const float4*)&frow[w * 4 + i][ch * 4];
    #pragma unroll
    for (int rr = 0; rr < 4; rr++) {
      int r = ch * 4 + rr;
      const float2* wp = (const float2*)(Wout + (size_t)r * 384 + c0);
      float2 w0 = wp[0], w1 = wp[1], w2 = wp[2];
      float wv[6] = { w0.x, w0.y, w1.x, w1.y, w2.x, w2.y };
      #pragma unroll
      for (int i = 0; i < 4; i++) {
        float fv = ((const float*)&f4[i])[rr];
        #pragma unroll
        for (int j = 0; j < 6; j++) acc[i][j] += fv * wv[j];
      }
    }
  }
  #pragma unroll
  for (int i = 0; i < 4; i++)
    #pragma unroll
    for (int j = 0; j < 6; j++)
      out[(size_t)(p0 + w * 4 + i) * 384 + c0 + j] = acc[i][j];
}

// ---------------------------------------------------------------------------
extern "C" void kernel_launch(void* const* d_in, const int* in_sizes, int n_in,
                              void* d_out, int out_size, void* d_ws, size_t ws_size,
                              hipStream_t stream) {
  const float* s      = (const float*)d_in[0];
  const float* z      = (const float*)d_in[1];
  const float* trans  = (const float*)d_in[2];
  const float* rots   = (const float*)d_in[3];
  const float* s_mask = (const float*)d_in[4];
  const int*   key_idx= (const int*)d_in[5];
  const float* ln_s_g = (const float*)d_in[6];
  const float* ln_s_b = (const float*)d_in[7];
  const float* ln_z_g = (const float*)d_in[8];
  const float* ln_z_b = (const float*)d_in[9];
  const float* Wq     = (const float*)d_in[10];
  const float* Wk     = (const float*)d_in[11];
  const float* Wv     = (const float*)d_in[12];
  const float* Wqp    = (const float*)d_in[13];
  const float* Wkvp   = (const float*)d_in[14];
  const float* Wb     = (const float*)d_in[15];
  const float* Wdz    = (const float*)d_in[16];
  const float* head_w = (const float*)d_in[17];
  const float* Wout   = (const float*)d_in[18];

  char* wsb = (char*)d_ws;
  float* posq  = (float*)(wsb + 0);          // 2*2048*192 f32
  float* posk  = (float*)(wsb + 3145728);
  float* posv  = (float*)(wsb + 6291456);
  float* posqp = (float*)(wsb + 9437184);    // 2*2048*144
  float* poskp = (float*)(wsb + 11796480);
  float* posvp = (float*)(wsb + 14155776);   // 2*2048*288
  float* posqn = (float*)(wsb + 18874368);   // 2*2048*12
  float* poskn = (float*)(wsb + 19070976);
  float* feats = (float*)(wsb + 19267584);   // 4096*960 f32 (15.7 MB)
  float* sN    = (float*)(wsb + 19267584);   // shares feats (dead before k_attn)
  float* proj  = (float*)(wsb + 34996224);   // shares bbias_t region (dead before k_z)
  ushort_t* bbias_t = (ushort_t*)(wsb + 34996224);  // 12,582,912 B
  ushort_t* pzt     = (ushort_t*)(wsb + 47579136);  // 33,554,432 B
  ushort_t* P_ws    = (ushort_t*)(wsb + 81133568);  // 12,582,912 B
  ushort_t* Wt_ws   = (ushort_t*)(wsb + 93716480);  // 12,288 B (in former slack)
  float*    uv_ws   = (float*)(wsb + 93728768);     // 384 B
  // total: 93,729,152 bytes (<= prior 93,749,248 footprint)

  k_ln<<<513, 256, 0, stream>>>(s, ln_s_g, ln_s_b, sN,
                                ln_z_g, ln_z_b, Wb, Wdz, Wt_ws, uv_ws);
  k_pgemm<<<1152, 256, 0, stream>>>(sN, Wq, Wk, Wv, Wqp, Wkvp, proj);
  k_rot<<<512, 256, 0, stream>>>(proj, trans, rots,
                                 posq, posk, posv, posqp, poskp, posvp, posqn, poskn);
  k_z<<<8192, 256, 0, stream>>>(z, Wt_ws, uv_ws, bbias_t, pzt);
  k_attn<<<768, 256, 0, stream>>>(posq, posk, posv, posqp, poskp, posvp, posqn, poskn,
                                  bbias_t, s_mask, key_idx, trans, rots, head_w,
                                  feats, P_ws);
  k_opair<<<1024, 256, 0, stream>>>(P_ws, pzt, feats);
  k_out<<<256, 256, 0, stream>>>(feats, Wout, (float*)d_out);
}

// Round 2
// 654.428 us; speedup vs baseline: 1.1748x; 1.0285x over previous
//
#include <hip/hip_runtime.h>
#include <hip/hip_bf16.h>

// Problem constants (BlockInvariantPointAttention):
// B=2 N=2048 BQ=32 BK=128 NB=64 CS=384 CZ=128 CH=16 H=12 PQK=4 PV=8
// feats per row: o(192) | o_pt_f(288) | o_pt_d(96) | o_pair(384) = 960
// All float inputs/outputs are FLOAT32; key_idx int32.
// Attention path: MFMA head-pair blocks; logits contraction = [16 qk | 12 pt | 4 pad]
//   with scales folded into Kext (0.1443 on qk part, -2*hwe_h on pt part).

typedef unsigned int uint_t;
typedef unsigned short ushort_t;
__device__ __forceinline__ float b2f(const __hip_bfloat16 x) { return __bfloat162float(x); }
__device__ __forceinline__ __hip_bfloat16 f2b(float x) { return __float2bfloat16(x); }
__device__ __forceinline__ ushort_t f2bu(float x) {
  __hip_bfloat16 h = __float2bfloat16(x);
  return *(ushort_t*)&h;
}
__device__ __forceinline__ float b2fu(ushort_t u) {
  union { uint_t i; float f; } c; c.i = ((uint_t)u) << 16; return c.f;
}
__device__ __forceinline__ uint_t pack2(float a, float b) {
  return (uint_t)f2bu(a) | ((uint_t)f2bu(b) << 16);
}
typedef __attribute__((ext_vector_type(8))) short short8x;   // 8 bf16 (4 VGPRs)
typedef __attribute__((ext_vector_type(4))) float floatx4;   // MFMA accumulator

// ---------------------------------------------------------------------------
// K0: LayerNorm of s -> sN.  Block 512 (extra) precomputes the block-invariant
// z-path weight tile Wt (bf16, [48][128]) plus uu[48]/vv[48] correction terms.
// ---------------------------------------------------------------------------
__global__ __launch_bounds__(256) void k_ln(
    const float* __restrict__ s, const float* __restrict__ g_s,
    const float* __restrict__ b_s, float* __restrict__ sN,
    const float* __restrict__ g_z, const float* __restrict__ b_z,
    const float* __restrict__ Wb, const float* __restrict__ Wdz,
    ushort_t* __restrict__ Wt_g, float* __restrict__ uv_g)
{
  if (blockIdx.x >= 512) {
    // --- weight prep block ---
    const int tid = threadIdx.x;
    for (int e = tid; e < 48 * 128; e += 256) {
      int c = e >> 7, k = e & 127;
      float v = 0.f;
      if (c < 12)      v = g_z[k] * Wb[k * 12 + c];
      else if (c < 44) v = g_z[k] * Wdz[k * 32 + (c - 12)];
      Wt_g[e] = f2bu(v);
    }
    int c = tid >> 2, p = tid & 3;
    float us_ = 0.f, vs_ = 0.f;
    if (c < 44) {
      for (int k = p * 32; k < p * 32 + 32; k++) {
        float worig = (c < 12) ? Wb[k * 12 + c] : Wdz[k * 32 + (c - 12)];
        us_ += b2fu(f2bu(g_z[k] * worig));   // matches bf16-rounded MFMA weights
        vs_ += b_z[k] * worig;
      }
    }
    us_ += __shfl_xor(us_, 1, 64); us_ += __shfl_xor(us_, 2, 64);
    vs_ += __shfl_xor(vs_, 1, 64); vs_ += __shfl_xor(vs_, 2, 64);
    if (p == 0 && c < 48) { uv_g[c] = us_; uv_g[48 + c] = vs_; }
    return;
  }
  const int tid = threadIdx.x;
  const int w = tid >> 6, l = tid & 63;
  #pragma unroll
  for (int ii = 0; ii < 2; ii++) {
    int row = blockIdx.x * 8 + w * 2 + ii;
    const float* sr = s + (size_t)row * 384;
    float x[6], s1 = 0.f, s2 = 0.f;
    #pragma unroll
    for (int j = 0; j < 6; j++) { x[j] = sr[l + j * 64]; s1 += x[j]; s2 += x[j] * x[j]; }
    #pragma unroll
    for (int m = 1; m < 64; m <<= 1) { s1 += __shfl_xor(s1, m, 64); s2 += __shfl_xor(s2, m, 64); }
    float mean = s1 * (1.f / 384.f);
    float var = s2 * (1.f / 384.f) - mean * mean;
    float rstd = rsqrtf(var + 1e-5f);
    float* dr = sN + (size_t)row * 384;
    #pragma unroll
    for (int j = 0; j < 6; j++) {
      int c = l + j * 64;
      dr[c] = (x[j] - mean) * rstd * g_s[c] + b_s[c];
    }
  }
}

// ---------------------------------------------------------------------------
// K1: FUSED  [blocks 0..1151]  proj = sN(4096x384) @ Wcat(384x1152)
//            [blocks 1152..9343]  z path (LDS-free MFMA)
// The two halves are data-independent (pgemm needs only sN; z-path needs only
// z + Wt/uv) and pipe-complementary (VALU-bound vs HBM-bound) -> co-resident
// blocks overlap the two costs inside one dispatch.
// ---------------------------------------------------------------------------
__global__ __launch_bounds__(256) void k_zpg(
    const float* __restrict__ sN,
    const float* __restrict__ Wq, const float* __restrict__ Wk,
    const float* __restrict__ Wv, const float* __restrict__ Wqp,
    const float* __restrict__ Wkvp,
    float* __restrict__ proj,
    const float* __restrict__ z,
    const ushort_t* __restrict__ Wt_g, const float* __restrict__ uv_g,
    ushort_t* __restrict__ bbias_t, ushort_t* __restrict__ pzt)
{
  if (blockIdx.x < 1152) {
    // ======================= pgemm half =======================
    __shared__ __align__(16) float sA[16][32];
    __shared__ __align__(16) float sB[16][128];
    const int tid = threadIdx.x;
    const int bid = blockIdx.x;
    const int mt = bid & 127;
    const int nt = bid >> 7;
    const int m0 = mt * 32, n0 = nt * 128;
    const int tm = tid >> 5, tn = tid & 31;

    const float* bsrc[2]; int bstride[2]; int bk[2];
    #pragma unroll
    for (int u = 0; u < 2; u++) {
      int idx = tid + u * 256;
      int k = idx >> 5, n4 = idx & 31;
      int col0 = n0 + n4 * 4;
      const float* p; int st;
      if (col0 < 192)      { p = Wq   + col0;         st = 192; }
      else if (col0 < 384) { p = Wk   + (col0 - 192); st = 192; }
      else if (col0 < 576) { p = Wv   + (col0 - 384); st = 192; }
      else if (col0 < 720) { p = Wqp  + (col0 - 576); st = 144; }
      else                 { p = Wkvp + (col0 - 720); st = 432; }
      bsrc[u] = p; bstride[u] = st; bk[u] = k;
    }
    const int am = tid >> 2, ak4 = tid & 3;

    float acc[4][4];
    #pragma unroll
    for (int i = 0; i < 4; i++)
      #pragma unroll
      for (int j = 0; j < 4; j++) acc[i][j] = 0.f;

    for (int k0 = 0; k0 < 384; k0 += 16) {
      #pragma unroll
      for (int u = 0; u < 2; u++) {
        float4 wv4 = *(const float4*)(bsrc[u] + (size_t)(k0 + bk[u]) * bstride[u]);
        *(float4*)&sB[bk[u]][(tid + u * 256 & 31) * 4] = wv4;
      }
      if (tid < 128) {
        float4 a4 = *(const float4*)(sN + (size_t)(m0 + am) * 384 + k0 + ak4 * 4);
        sA[ak4 * 4 + 0][am] = a4.x;
        sA[ak4 * 4 + 1][am] = a4.y;
        sA[ak4 * 4 + 2][am] = a4.z;
        sA[ak4 * 4 + 3][am] = a4.w;
      }
      __syncthreads();
      #pragma unroll
      for (int kk = 0; kk < 16; kk++) {
        float4 a4 = *(const float4*)&sA[kk][tm * 4];
        float4 b4 = *(const float4*)&sB[kk][tn * 4];
        const float* av = (const float*)&a4;
        const float* bv = (const float*)&b4;
        #pragma unroll
        for (int i = 0; i < 4; i++)
          #pragma unroll
          for (int j = 0; j < 4; j++) acc[i][j] += av[i] * bv[j];
      }
      __syncthreads();
    }
    #pragma unroll
    for (int i = 0; i < 4; i++)
      *(float4*)(proj + (size_t)(m0 + tm * 4 + i) * 1152 + n0 + tn * 4) = *(float4*)&acc[i][0];
  } else {
    // ======================= z half (no LDS, no barriers) =======================
    const int tid = threadIdx.x;
    const int bid = blockIdx.x - 1152;
    const int w = tid >> 6, lane = tid & 63, quad = lane >> 4, r16 = lane & 15;
    const size_t row0 = (size_t)bid * 64;
    const int lrow = w * 16 + r16;                 // this lane's A row (0..63)
    const float* zr = z + (row0 + lrow) * 128;

    // B fragments (loop-invariant), from global Wt tile: rows 44..47 are zeros.
    short8x bf[3][4];
    #pragma unroll
    for (int nt = 0; nt < 3; nt++)
      #pragma unroll
      for (int kk = 0; kk < 4; kk++)
        bf[nt][kk] = *(const short8x*)(Wt_g + (size_t)(nt * 16 + r16) * 128 + kk * 32 + quad * 8);

    // A fragments: 32 raw z floats per lane, cols {quad*8 + kk*32 .. +7}.
    union { short8x v; uint_t u[4]; } afu[4];
    float s1 = 0.f, s2 = 0.f;
    #pragma unroll
    for (int kk = 0; kk < 4; kk++) {
      float4 a = *(const float4*)(zr + kk * 32 + quad * 8);
      float4 b = *(const float4*)(zr + kk * 32 + quad * 8 + 4);
      s1 += a.x + a.y + a.z + a.w + b.x + b.y + b.z + b.w;
      s2 += a.x * a.x + a.y * a.y + a.z * a.z + a.w * a.w
          + b.x * b.x + b.y * b.y + b.z * b.z + b.w * b.w;
      afu[kk].u[0] = pack2(a.x, a.y);
      afu[kk].u[1] = pack2(a.z, a.w);
      afu[kk].u[2] = pack2(b.x, b.y);
      afu[kk].u[3] = pack2(b.z, b.w);
    }
    // Row stats: combine the 4 quad-lanes that share r16 (xor 16, 32).
    s1 += __shfl_xor(s1, 16, 64); s1 += __shfl_xor(s1, 32, 64);
    s2 += __shfl_xor(s2, 16, 64); s2 += __shfl_xor(s2, 32, 64);
    float mean = s1 * (1.f / 128.f);
    float rstd = rsqrtf(s2 * (1.f / 128.f) - mean * mean + 1e-5f);

    floatx4 acc[3] = { {0,0,0,0}, {0,0,0,0}, {0,0,0,0} };
    #pragma unroll
    for (int kk = 0; kk < 4; kk++)
      #pragma unroll
      for (int nt = 0; nt < 3; nt++)
        acc[nt] = __builtin_amdgcn_mfma_f32_16x16x32_bf16(afu[kk].v, bf[nt][kk], acc[nt], 0, 0, 0);

    // C layout: row = quad*4+reg, col = r16.  Fetch stats for output rows
    // w*16 + quad*4 + reg from the lane that owns that row (lane id = row&15).
    float mr[4], rr[4];
    #pragma unroll
    for (int reg = 0; reg < 4; reg++) {
      int src = quad * 4 + reg;
      mr[reg] = __shfl(mean, src, 64);
      rr[reg] = __shfl(rstd, src, 64);
    }

    const int bp = bid >> 6;                 // = b*64+nb
    const int qk0 = (bid & 63) * 64;         // local (q*128+k) base
    const int qloc = qk0 >> 7;               // q index 0..31
    const int kbase = (qk0 & 127) + w * 16 + quad * 4;
    #pragma unroll
    for (int nt = 0; nt < 3; nt++) {
      int c = nt * 16 + r16;
      if (c < 44) {
        float uc = uv_g[c], vc = uv_g[48 + c];
        float vals[4];
        #pragma unroll
        for (int reg = 0; reg < 4; reg++)
          vals[reg] = rr[reg] * acc[nt][reg] - mr[reg] * rr[reg] * uc + vc;
        uint2 pk = make_uint2(pack2(vals[0], vals[1]), pack2(vals[2], vals[3]));
        if (c < 12) {
          size_t el = (((size_t)(bp * 12 + c)) << 12) + qk0 + w * 16 + quad * 4;
          *(uint2*)(bbias_t + el) = pk;
        } else {
          size_t el = (((size_t)((bp * 32 + qloc) * 32 + (c - 12))) << 7) + kbase;
          *(uint2*)(pzt + el) = pk;
        }
      }
    }
  }
}

// ---------------------------------------------------------------------------
// K2: rotations + point norms + scatter to pos* buffers. 8 positions/block.
// ---------------------------------------------------------------------------
__global__ __launch_bounds__(256) void k_rot(
    const float* __restrict__ proj_g,
    const float* __restrict__ trans, const float* __restrict__ rots,
    float* __restrict__ posq, float* __restrict__ posk, float* __restrict__ posv,
    float* __restrict__ posqp, float* __restrict__ poskp, float* __restrict__ posvp,
    float* __restrict__ posqn, float* __restrict__ poskn)
{
  __shared__ __align__(16) float proj[8][1152];
  __shared__ float rt[8][12];
  const int tid = threadIdx.x;
  const int p0 = blockIdx.x * 8;

  for (int e = tid; e < 8 * 288; e += 256)
    ((float4*)&proj[0][0])[e] = ((const float4*)(proj_g + (size_t)p0 * 1152))[e];
  for (int e = tid; e < 8 * 12; e += 256) {
    int i = e / 12, c = e % 12;
    rt[i][c] = (c < 9) ? rots[(size_t)(p0 + i) * 9 + c]
                       : trans[(size_t)(p0 + i) * 3 + (c - 9)];
  }
  __syncthreads();

  for (int e = tid; e < 8 * 192; e += 256) {
    int i = e / 192, p = e % 192;
    float R0 = rt[i][0], R1 = rt[i][1], R2 = rt[i][2];
    float R3 = rt[i][3], R4 = rt[i][4], R5 = rt[i][5];
    float R6 = rt[i][6], R7 = rt[i][7], R8 = rt[i][8];
    float tx = rt[i][9], ty = rt[i][10], tz = rt[i][11];
    size_t pos = p0 + i;
    if (p < 48) {
      int base = 576 + p * 3;
      float v0 = proj[i][base], v1 = proj[i][base + 1], v2 = proj[i][base + 2];
      float o0 = R0 * v0 + R1 * v1 + R2 * v2 + tx;
      float o1 = R3 * v0 + R4 * v1 + R5 * v2 + ty;
      float o2 = R6 * v0 + R7 * v1 + R8 * v2 + tz;
      proj[i][base] = o0; proj[i][base + 1] = o1; proj[i][base + 2] = o2;
      posqp[pos * 144 + p * 3 + 0] = o0;
      posqp[pos * 144 + p * 3 + 1] = o1;
      posqp[pos * 144 + p * 3 + 2] = o2;
    } else {
      int p2 = p - 48;
      int base = 720 + p2 * 3;
      float v0 = proj[i][base], v1 = proj[i][base + 1], v2 = proj[i][base + 2];
      float o0 = R0 * v0 + R1 * v1 + R2 * v2 + tx;
      float o1 = R3 * v0 + R4 * v1 + R5 * v2 + ty;
      float o2 = R6 * v0 + R7 * v1 + R8 * v2 + tz;
      int h = p2 / 12, idx = p2 % 12;
      if (idx < 4) {
        proj[i][base] = o0; proj[i][base + 1] = o1; proj[i][base + 2] = o2;
        poskp[pos * 144 + h * 12 + idx * 3 + 0] = o0;
        poskp[pos * 144 + h * 12 + idx * 3 + 1] = o1;
        poskp[pos * 144 + h * 12 + idx * 3 + 2] = o2;
      } else {
        posvp[pos * 288 + h * 24 + (idx - 4) * 3 + 0] = o0;
        posvp[pos * 288 + h * 24 + (idx - 4) * 3 + 1] = o1;
        posvp[pos * 288 + h * 24 + (idx - 4) * 3 + 2] = o2;
      }
    }
  }
  __syncthreads();

  for (int e = tid; e < 96; e += 256) {
    int i = e / 12, h = e % 12;
    size_t pos = p0 + i;
    float qs = 0.f, ks = 0.f;
    #pragma unroll
    for (int u = 0; u < 12; u++) {
      float a_ = proj[i][576 + h * 12 + u];
      qs += a_ * a_;
      float c_ = proj[i][720 + h * 36 + u];
      ks += c_ * c_;
    }
    posqn[pos * 12 + h] = qs;
    poskn[pos * 12 + h] = ks;
  }
  for (int e = tid; e < 8 * 576; e += 256) {
    int i = e / 576, c = e % 576;
    size_t pos = p0 + i;
    float v = proj[i][c];
    if (c < 192)      posq[pos * 192 + c]         = v;
    else if (c < 384) posk[pos * 192 + (c - 192)] = v;
    else              posv[pos * 192 + (c - 384)] = v;
  }
}

// ---------------------------------------------------------------------------
// K4: attention. 768 blocks = (b, nb, head-pair). 4 waves = (head, q-half).
// Per wave: 8 logits MFMA -> in-register softmax -> 12 PV MFMA -> epilogues.
// ---------------------------------------------------------------------------
__global__ __launch_bounds__(256) void k_attn(
    const float* __restrict__ posq, const float* __restrict__ posk,
    const float* __restrict__ posv, const float* __restrict__ posqp,
    const float* __restrict__ poskp, const float* __restrict__ posvp,
    const float* __restrict__ posqn, const float* __restrict__ poskn,
    const ushort_t* __restrict__ bbias_t,
    const float* __restrict__ s_mask, const int* __restrict__ key_idx,
    const float* __restrict__ trans, const float* __restrict__ rots,
    const float* __restrict__ head_w,
    float* __restrict__ feats, ushort_t* __restrict__ P_ws)
{
  __shared__ __align__(16) ushort_t sK[2 * 128 * 40];  // Kext [hh][k][40] (use 0..31)
  __shared__ __align__(16) ushort_t sV[2 * 48 * 136];  // Vext [hh][c][136] (k 0..127)
  __shared__ __align__(16) ushort_t sQ[2 * 32 * 40];   // Qext [hh][q][40]
  __shared__ __align__(16) ushort_t sP[64 * 136];      // P    [w*16+row][136]
  __shared__ float sOpt[64 * 25];                      // o_pt raw [w*16+row][25]
  __shared__ float rt[32][12];
  __shared__ float kn_l[2][128];
  __shared__ float qn_l[2][32];
  __shared__ float kmask[128];
  __shared__ float qmask[32];
  __shared__ int   kidx[128];
  __shared__ float hwe2[2];

  const int tid = threadIdx.x;
  const int bid = blockIdx.x;
  const int b = bid / 384;
  const int rem = bid % 384;
  const int nb = rem / 6;
  const int hp = rem % 6;
  const int h0 = hp * 2;
  const int rowbase = b * 2048 + nb * 32;

  if (tid < 128) kidx[tid] = key_idx[nb * 128 + tid];
  if (tid < 2) hwe2[tid] = -0.5f * 0.13608276348795434f * log1pf(expf(head_w[h0 + tid]));
  __syncthreads();

  if (tid < 128) kmask[tid] = s_mask[b * 2048 + kidx[tid]];
  if (tid < 32) qmask[tid] = s_mask[rowbase + tid];
  for (int e = tid; e < 384; e += 256) {
    int i = e / 12, c = e % 12;
    rt[i][c] = (c < 9) ? rots[(size_t)(rowbase + i) * 9 + c]
                       : trans[(size_t)(rowbase + i) * 3 + (c - 9)];
  }

  // ---- Kext + kn staging: thread <-> (hh, k) ----
  {
    int hh = tid >> 7, k = tid & 127, h = h0 + hh;
    int gk = b * 2048 + kidx[k];
    kn_l[hh][k] = poskn[(size_t)gk * 12 + h];
    float sq = 0.14433756729740643f;
    float sp = -2.f * hwe2[hh];
    const float* kr = posk + (size_t)gk * 192 + h * 16;
    #pragma unroll
    for (int c4 = 0; c4 < 4; c4++) {
      float4 v4 = *(const float4*)(kr + c4 * 4);
      uint2 pk = make_uint2(pack2(sq * v4.x, sq * v4.y), pack2(sq * v4.z, sq * v4.w));
      *(uint2*)&sK[(hh * 128 + k) * 40 + c4 * 4] = pk;
    }
    const float* kpr = poskp + (size_t)gk * 144 + h * 12;
    #pragma unroll
    for (int c4 = 0; c4 < 3; c4++) {
      float4 v4 = *(const float4*)(kpr + c4 * 4);
      uint2 pk = make_uint2(pack2(sp * v4.x, sp * v4.y), pack2(sp * v4.z, sp * v4.w));
      *(uint2*)&sK[(hh * 128 + k) * 40 + 16 + c4 * 4] = pk;
    }
    *(uint2*)&sK[(hh * 128 + k) * 40 + 28] = make_uint2(0u, 0u);
  }
  // ---- Vext staging (transposed, k-pairs packed): thread <-> (hh, k-pair, c-half) ----
  {
    int hh = tid >> 7, t7 = tid & 127, h = h0 + hh;
    int k2 = t7 >> 1, cg = t7 & 1, kk0 = k2 * 2;
    int ga = b * 2048 + kidx[kk0], gb = b * 2048 + kidx[kk0 + 1];
    if (cg == 0) {
      const float* A_ = posv + (size_t)ga * 192 + h * 16;
      const float* B_ = posv + (size_t)gb * 192 + h * 16;
      #pragma unroll
      for (int c4 = 0; c4 < 4; c4++) {
        float4 a4 = *(const float4*)(A_ + c4 * 4);
        float4 b4 = *(const float4*)(B_ + c4 * 4);
        #pragma unroll
        for (int j = 0; j < 4; j++)
          *(uint_t*)&sV[(hh * 48 + c4 * 4 + j) * 136 + kk0] =
              pack2(((const float*)&a4)[j], ((const float*)&b4)[j]);
      }
    } else {
      const float* A_ = posvp + (size_t)ga * 288 + h * 24;
      const float* B_ = posvp + (size_t)gb * 288 + h * 24;
      #pragma unroll
      for (int c4 = 0; c4 < 6; c4++) {
        float4 a4 = *(const float4*)(A_ + c4 * 4);
        float4 b4 = *(const float4*)(B_ + c4 * 4);
        #pragma unroll
        for (int j = 0; j < 4; j++)
          *(uint_t*)&sV[(hh * 48 + 16 + c4 * 4 + j) * 136 + kk0] =
              pack2(((const float*)&a4)[j], ((const float*)&b4)[j]);
      }
      #pragma unroll
      for (int j = 0; j < 8; j++)
        *(uint_t*)&sV[(hh * 48 + 40 + j) * 136 + kk0] = 0u;
    }
  }
  // ---- Qext + qn staging: thread <-> (hh, q), tid<64 ----
  if (tid < 64) {
    int hh = tid >> 5, q = tid & 31, h = h0 + hh;
    qn_l[hh][q] = posqn[(size_t)(rowbase + q) * 12 + h];
    const float* qr = posq + (size_t)(rowbase + q) * 192 + h * 16;
    #pragma unroll
    for (int c4 = 0; c4 < 4; c4++) {
      float4 v4 = *(const float4*)(qr + c4 * 4);
      uint2 pk = make_uint2(pack2(v4.x, v4.y), pack2(v4.z, v4.w));
      *(uint2*)&sQ[(hh * 32 + q) * 40 + c4 * 4] = pk;
    }
    const float* qpr = posqp + (size_t)(rowbase + q) * 144 + h * 12;
    #pragma unroll
    for (int c4 = 0; c4 < 3; c4++) {
      float4 v4 = *(const float4*)(qpr + c4 * 4);
      uint2 pk = make_uint2(pack2(v4.x, v4.y), pack2(v4.z, v4.w));
      *(uint2*)&sQ[(hh * 32 + q) * 40 + 16 + c4 * 4] = pk;
    }
    *(uint2*)&sQ[(hh * 32 + q) * 40 + 28] = make_uint2(0u, 0u);
  }
  __syncthreads();

  // ---- per-wave compute ----
  const int w = tid >> 6, lane = tid & 63, quad = lane >> 4, r16 = lane & 15;
  const int hh = w >> 1, q0 = (w & 1) * 16;
  const int h = h0 + hh;
  const float hwe = hwe2[hh];

  short8x af = *(const short8x*)&sQ[(hh * 32 + q0 + r16) * 40 + quad * 8];
  floatx4 acc[8];
  #pragma unroll
  for (int nt = 0; nt < 8; nt++) {
    floatx4 z4 = {0.f, 0.f, 0.f, 0.f};
    short8x bf = *(const short8x*)&sK[(hh * 128 + nt * 16 + r16) * 40 + quad * 8];
    acc[nt] = __builtin_amdgcn_mfma_f32_16x16x32_bf16(af, bf, z4, 0, 0, 0);
  }

  const ushort_t* bb = bbias_t + (((size_t)((b * 64 + nb) * 12 + h)) << 12);
  float lg[8][4];
  #pragma unroll
  for (int nt = 0; nt < 8; nt++)
    #pragma unroll
    for (int reg = 0; reg < 4; reg++) {
      int qa = q0 + quad * 4 + reg;
      lg[nt][reg] = b2fu(bb[qa * 128 + nt * 16 + r16]);
    }
  float qnv[4], qmv[4];
  #pragma unroll
  for (int reg = 0; reg < 4; reg++) {
    int qa = q0 + quad * 4 + reg;
    qnv[reg] = qn_l[hh][qa]; qmv[reg] = qmask[qa];
  }
  #pragma unroll
  for (int nt = 0; nt < 8; nt++) {
    int col = nt * 16 + r16;
    float knv = kn_l[hh][col], kmv = kmask[col];
    #pragma unroll
    for (int reg = 0; reg < 4; reg++)
      lg[nt][reg] = acc[nt][reg] + 0.5773502691896258f * lg[nt][reg]
                  + hwe * (qnv[reg] + knv) + 100000.f * (qmv[reg] * kmv - 1.f);
  }
  // softmax over 128 keys per row (in-lane over nt, xor-shuffle over r16)
  float mx[4], sm[4];
  #pragma unroll
  for (int reg = 0; reg < 4; reg++) {
    float m = lg[0][reg];
    #pragma unroll
    for (int nt = 1; nt < 8; nt++) m = fmaxf(m, lg[nt][reg]);
    #pragma unroll
    for (int d = 1; d < 16; d <<= 1) m = fmaxf(m, __shfl_xor(m, d, 64));
    mx[reg] = m; sm[reg] = 0.f;
  }
  #pragma unroll
  for (int nt = 0; nt < 8; nt++)
    #pragma unroll
    for (int reg = 0; reg < 4; reg++) {
      float e = __expf(lg[nt][reg] - mx[reg]);
      lg[nt][reg] = e; sm[reg] += e;
    }
  #pragma unroll
  for (int reg = 0; reg < 4; reg++) {
    float s = sm[reg];
    #pragma unroll
    for (int d = 1; d < 16; d <<= 1) s += __shfl_xor(s, d, 64);
    sm[reg] = 1.f / s;
  }
  // P -> LDS (wave-private)
  #pragma unroll
  for (int nt = 0; nt < 8; nt++)
    #pragma unroll
    for (int reg = 0; reg < 4; reg++) {
      int row = quad * 4 + reg;
      sP[(w * 16 + row) * 136 + nt * 16 + r16] = f2bu(lg[nt][reg] * sm[reg]);
    }
  // PV
  short8x afp[4];
  #pragma unroll
  for (int kk = 0; kk < 4; kk++)
    afp[kk] = *(const short8x*)&sP[(w * 16 + r16) * 136 + kk * 32 + quad * 8];
  floatx4 o0 = {0.f,0.f,0.f,0.f}, o1 = {0.f,0.f,0.f,0.f}, o2 = {0.f,0.f,0.f,0.f};
  #pragma unroll
  for (int kk = 0; kk < 4; kk++) {
    short8x bv0 = *(const short8x*)&sV[(hh * 48 +  0 + r16) * 136 + kk * 32 + quad * 8];
    short8x bv1 = *(const short8x*)&sV[(hh * 48 + 16 + r16) * 136 + kk * 32 + quad * 8];
    short8x bv2 = *(const short8x*)&sV[(hh * 48 + 32 + r16) * 136 + kk * 32 + quad * 8];
    o0 = __builtin_amdgcn_mfma_f32_16x16x32_bf16(afp[kk], bv0, o0, 0, 0, 0);
    o1 = __builtin_amdgcn_mfma_f32_16x16x32_bf16(afp[kk], bv1, o1, 0, 0, 0);
    o2 = __builtin_amdgcn_mfma_f32_16x16x32_bf16(afp[kk], bv2, o2, 0, 0, 0);
  }
  // o epilogue (cols 0..15 = c)
  #pragma unroll
  for (int reg = 0; reg < 4; reg++) {
    int qa = q0 + quad * 4 + reg;
    feats[(size_t)(rowbase + qa) * 960 + h * 16 + r16] = o0[reg];
  }
  // o_pt raw -> LDS
  #pragma unroll
  for (int reg = 0; reg < 4; reg++) {
    int row = quad * 4 + reg;
    sOpt[(w * 16 + row) * 25 + r16] = o1[reg];
    if (r16 < 8) sOpt[(w * 16 + row) * 25 + 16 + r16] = o2[reg];
  }
  // rotation + norm epilogue (same wave; LDS deps via waitcnt)
  for (int e2 = lane; e2 < 128; e2 += 64) {
    int ql = e2 >> 3, v = e2 & 7;
    int qa = q0 + ql;
    float u0 = sOpt[(w * 16 + ql) * 25 + v * 3 + 0] - rt[qa][9];
    float u1 = sOpt[(w * 16 + ql) * 25 + v * 3 + 1] - rt[qa][10];
    float u2 = sOpt[(w * 16 + ql) * 25 + v * 3 + 2] - rt[qa][11];
    float w0 = rt[qa][0] * u0 + rt[qa][3] * u1 + rt[qa][6] * u2;
    float w1 = rt[qa][1] * u0 + rt[qa][4] * u1 + rt[qa][7] * u2;
    float w2 = rt[qa][2] * u0 + rt[qa][5] * u1 + rt[qa][8] * u2;
    size_t fb = (size_t)(rowbase + qa) * 960;
    feats[fb + 192 + h * 24 + v * 3 + 0] = w0;
    feats[fb + 192 + h * 24 + v * 3 + 1] = w1;
    feats[fb + 192 + h * 24 + v * 3 + 2] = w2;
    feats[fb + 480 + h * 8 + v] = sqrtf(w0 * w0 + w1 * w1 + w2 * w2 + 1e-8f);
  }
  // P -> global (for k_opair), coalesced uint stores
  {
    uint_t* Pg = (uint_t*)P_ws;
    size_t pb2 = (((size_t)((b * 64 + nb) * 12 + h)) << 12) >> 1;  // uint index base
    #pragma unroll
    for (int ql = 0; ql < 16; ql++) {
      uint_t pv = *(const uint_t*)&sP[(w * 16 + ql) * 136 + 2 * lane];
      Pg[pb2 + (size_t)(q0 + ql) * 64 + lane] = pv;
    }
  }
}

// ---------------------------------------------------------------------------
// K5: o_pair. 1024 blocks = (b, nb, q-quad). wave <-> q.
// A = P [m=h(pad16)][k=key] from global; B = pzt [n=c][k=key] via LDS.
// ---------------------------------------------------------------------------
__global__ __launch_bounds__(256) void k_opair(
    const ushort_t* __restrict__ P_ws, const ushort_t* __restrict__ pzt,
    float* __restrict__ feats)
{
  __shared__ __align__(16) ushort_t pzl[4 * 32 * 136];
  const int tid = threadIdx.x;
  const int w = tid >> 6, lane = tid & 63, quad = lane >> 4, r16 = lane & 15;
  const int bid = blockIdx.x;
  const int b = bid >> 9, rem = bid & 511, nb = rem >> 3, qg = rem & 7;
  const int q = qg * 4 + w;
  const int rowbase = b * 2048 + nb * 32;

  // stage this wave's pz tile (transposed layout already): 32 c-rows x 128 k
  const uint_t* src = (const uint_t*)pzt + ((((size_t)((b * 64 + nb) * 32 + q)) << 12) >> 1);
  #pragma unroll
  for (int c = 0; c < 32; c++) {
    uint_t v = src[c * 64 + lane];
    *(uint_t*)&pzl[(w * 32 + c) * 136 + 2 * lane] = v;
  }
  // A-frags from global P
  const ushort_t* Pp = P_ws + ((size_t)(b * 64 + nb) * 12) * 4096
                            + (size_t)r16 * 4096 + (size_t)q * 128;
  short8x af[4];
  #pragma unroll
  for (int kk = 0; kk < 4; kk++)
    af[kk] = *(const short8x*)(Pp + kk * 32 + quad * 8);

  floatx4 acc[2] = { {0.f,0.f,0.f,0.f}, {0.f,0.f,0.f,0.f} };
  #pragma unroll
  for (int kk = 0; kk < 4; kk++) {
    #pragma unroll
    for (int nt = 0; nt < 2; nt++) {
      short8x bf = *(const short8x*)&pzl[(w * 32 + nt * 16 + r16) * 136 + kk * 32 + quad * 8];
      acc[nt] = __builtin_amdgcn_mfma_f32_16x16x32_bf16(af[kk], bf, acc[nt], 0, 0, 0);
    }
  }
  #pragma unroll
  for (int nt = 0; nt < 2; nt++)
    #pragma unroll
    for (int reg = 0; reg < 4; reg++) {
      int hrow = quad * 4 + reg;
      if (hrow < 12)
        feats[(size_t)(rowbase + q) * 960 + 576 + hrow * 32 + nt * 16 + r16] = acc[nt][reg];
    }
}

// ---------------------------------------------------------------------------
// K6: out = feats(4096x960) @ Wout(960x384). 16 rows per block.
// ---------------------------------------------------------------------------
__global__ __launch_bounds__(256) void k_out(
    const float* __restrict__ feats, const float* __restrict__ Wout,
    float* __restrict__ out)
{
  __shared__ __align__(16) float frow[16][960];
  const int tid = threadIdx.x;
  const int p0 = blockIdx.x * 16;
  for (int e = tid; e < 16 * 240; e += 256) {
    int i = e / 240, cc = e % 240;
    ((float4*)&frow[i][0])[cc] = ((const float4*)&feats[(size_t)(p0 + i) * 960])[cc];
  }
  __syncthreads();
  const int w = tid >> 6, l = tid & 63;
  const int c0 = l * 6;
  float acc[4][6];
  #pragma unroll
  for (int i = 0; i < 4; i++)
    #pragma unroll
    for (int j = 0; j < 6; j++) acc[i][j] = 0.f;

  for (int ch = 0; ch < 240; ch++) {
    float4 f4[4];
    #pragma unroll
    for (int i = 0; i < 4; i++) f4[i] = *(const float4*)&frow[w * 4 + i][ch * 4];
    #pragma unroll
    for (int rr = 0; rr < 4; rr++) {
      int r = ch * 4 + rr;
      const float2* wp = (const float2*)(Wout + (size_t)r * 384 + c0);
      float2 w0 = wp[0], w1 = wp[1], w2 = wp[2];
      float wv[6] = { w0.x, w0.y, w1.x, w1.y, w2.x, w2.y };
      #pragma unroll
      for (int i = 0; i < 4; i++) {
        float fv = ((const float*)&f4[i])[rr];
        #pragma unroll
        for (int j = 0; j < 6; j++) acc[i][j] += fv * wv[j];
      }
    }
  }
  #pragma unroll
  for (int i = 0; i < 4; i++)
    #pragma unroll
    for (int j = 0; j < 6; j++)
      out[(size_t)(p0 + w * 4 + i) * 384 + c0 + j] = acc[i][j];
}

// ---------------------------------------------------------------------------
extern "C" void kernel_launch(void* const* d_in, const int* in_sizes, int n_in,
                              void* d_out, int out_size, void* d_ws, size_t ws_size,
                              hipStream_t stream) {
  const float* s      = (const float*)d_in[0];
  const float* z      = (const float*)d_in[1];
  const float* trans  = (const float*)d_in[2];
  const float* rots   = (const float*)d_in[3];
  const float* s_mask = (const float*)d_in[4];
  const int*   key_idx= (const int*)d_in[5];
  const float* ln_s_g = (const float*)d_in[6];
  const float* ln_s_b = (const float*)d_in[7];
  const float* ln_z_g = (const float*)d_in[8];
  const float* ln_z_b = (const float*)d_in[9];
  const float* Wq     = (const float*)d_in[10];
  const float* Wk     = (const float*)d_in[11];
  const float* Wv     = (const float*)d_in[12];
  const float* Wqp    = (const float*)d_in[13];
  const float* Wkvp   = (const float*)d_in[14];
  const float* Wb     = (const float*)d_in[15];
  const float* Wdz    = (const float*)d_in[16];
  const float* head_w = (const float*)d_in[17];
  const float* Wout   = (const float*)d_in[18];

  char* wsb = (char*)d_ws;
  // Layout (de-aliased: proj/pzt/bbias_t may now be written CONCURRENTLY
  // inside the fused k_zpg launch, so no region sharing between them).
  float* posq  = (float*)(wsb + 0);          // 2*2048*192 f32
  float* posk  = (float*)(wsb + 3145728);
  float* posv  = (float*)(wsb + 6291456);
  float* posqp = (float*)(wsb + 9437184);    // 2*2048*144
  float* poskp = (float*)(wsb + 11796480);
  float* posvp = (float*)(wsb + 14155776);   // 2*2048*288
  float* posqn = (float*)(wsb + 18874368);   // 2*2048*12
  float* poskn = (float*)(wsb + 19070976);
  float* feats = (float*)(wsb + 19267584);   // 4096*960 f32 (15.7 MB)
  float* sN    = (float*)(wsb + 19267584);   // shares feats (dead before k_attn)
  float* proj  = (float*)(wsb + 34996224);   // 18,874,368 B  -> ends 53,870,592
  ushort_t* bbias_t = (ushort_t*)(wsb + 53870592);   // 12,582,912 B
  ushort_t* pzt     = (ushort_t*)(wsb + 66453504);   // 33,554,432 B
  ushort_t* P_ws    = (ushort_t*)(wsb + 100007936);  // 12,582,912 B
  ushort_t* Wt_ws   = (ushort_t*)(wsb + 112590848);  // 12,288 B
  float*    uv_ws   = (float*)(wsb + 112603136);     // 384 B
  // total: ~112.6 MB (ws is 1 GiB per the fill-buffer WRITE_SIZE)

  k_ln<<<513, 256, 0, stream>>>(s, ln_s_g, ln_s_b, sN,
                                ln_z_g, ln_z_b, Wb, Wdz, Wt_ws, uv_ws);
  // fused: blocks 0..1151 = pgemm, 1152..9343 = z path (independent halves)
  k_zpg<<<9344, 256, 0, stream>>>(sN, Wq, Wk, Wv, Wqp, Wkvp, proj,
                                  z, Wt_ws, uv_ws, bbias_t, pzt);
  k_rot<<<512, 256, 0, stream>>>(proj, trans, rots,
                                 posq, posk, posv, posqp, poskp, posvp, posqn, poskn);
  k_attn<<<768, 256, 0, stream>>>(posq, posk, posv, posqp, poskp, posvp, posqn, poskn,
                                  bbias_t, s_mask, key_idx, trans, rots, head_w,
                                  feats, P_ws);
  k_opair<<<1024, 256, 0, stream>>>(P_ws, pzt, feats);
  k_out<<<256, 256, 0, stream>>>(feats, Wout, (float*)d_out);
}

// Round 4
// 562.946 us; speedup vs baseline: 1.3657x; 1.1625x over previous
//
#include <hip/hip_runtime.h>
#include <hip/hip_bf16.h>

// Problem constants (BlockInvariantPointAttention):
// B=2 N=2048 BQ=32 BK=128 NB=64 CS=384 CZ=128 CH=16 H=12 PQK=4 PV=8
// feats per row: o(192) | o_pt_f(288) | o_pt_d(96) | o_pair(384) = 960
// All float inputs/outputs are FLOAT32; key_idx int32.
// Attention path: MFMA head-pair blocks; logits contraction = [16 qk | 12 pt | 4 pad]
//   with scales folded into Kext (0.1443 on qk part, -2*hwe_h on pt part).
// k_out: 3-term bf16 MFMA emulation of the fp32 GEMM (hi/lo split; error ~1e-5 rel).

typedef unsigned int uint_t;
typedef unsigned short ushort_t;
__device__ __forceinline__ float b2f(const __hip_bfloat16 x) { return __bfloat162float(x); }
__device__ __forceinline__ __hip_bfloat16 f2b(float x) { return __float2bfloat16(x); }
__device__ __forceinline__ ushort_t f2bu(float x) {
  __hip_bfloat16 h = __float2bfloat16(x);
  return *(ushort_t*)&h;
}
__device__ __forceinline__ float b2fu(ushort_t u) {
  union { uint_t i; float f; } c; c.i = ((uint_t)u) << 16; return c.f;
}
__device__ __forceinline__ uint_t pack2(float a, float b) {
  return (uint_t)f2bu(a) | ((uint_t)f2bu(b) << 16);
}
typedef __attribute__((ext_vector_type(8))) short short8x;   // 8 bf16 (4 VGPRs)
typedef __attribute__((ext_vector_type(4))) float floatx4;   // MFMA accumulator

// ---------------------------------------------------------------------------
// K0: LayerNorm of s -> sN.
//   block 512      : z-path weight tile Wt (bf16 [48][128]) + uu/vv terms
//   blocks 513..608: Wout transpose+split -> WoT_hi/WoT_lo [384][960] bf16
//                    (for the 3-term bf16 MFMA k_out)
// ---------------------------------------------------------------------------
__global__ __launch_bounds__(256) void k_ln(
    const float* __restrict__ s, const float* __restrict__ g_s,
    const float* __restrict__ b_s, float* __restrict__ sN,
    const float* __restrict__ g_z, const float* __restrict__ b_z,
    const float* __restrict__ Wb, const float* __restrict__ Wdz,
    ushort_t* __restrict__ Wt_g, float* __restrict__ uv_g,
    const float* __restrict__ Wout,
    ushort_t* __restrict__ woT_hi, ushort_t* __restrict__ woT_lo)
{
  if (blockIdx.x >= 513) {
    // --- Wout transpose + hi/lo split: 4 cols per block ---
    const int tid = threadIdx.x;
    const int c = (blockIdx.x - 513) * 4 + (tid >> 6);
    const int lane = tid & 63;
    for (int k0 = 0; k0 < 960; k0 += 64) {
      int k = k0 + lane;
      float x = Wout[(size_t)k * 384 + c];
      ushort_t hu = f2bu(x);
      woT_hi[(size_t)c * 960 + k] = hu;
      woT_lo[(size_t)c * 960 + k] = f2bu(x - b2fu(hu));
    }
    return;
  }
  if (blockIdx.x == 512) {
    // --- z-path weight prep block ---
    const int tid = threadIdx.x;
    for (int e = tid; e < 48 * 128; e += 256) {
      int c = e >> 7, k = e & 127;
      float v = 0.f;
      if (c < 12)      v = g_z[k] * Wb[k * 12 + c];
      else if (c < 44) v = g_z[k] * Wdz[k * 32 + (c - 12)];
      Wt_g[e] = f2bu(v);
    }
    int c = tid >> 2, p = tid & 3;
    float us_ = 0.f, vs_ = 0.f;
    if (c < 44) {
      for (int k = p * 32; k < p * 32 + 32; k++) {
        float worig = (c < 12) ? Wb[k * 12 + c] : Wdz[k * 32 + (c - 12)];
        us_ += b2fu(f2bu(g_z[k] * worig));   // matches bf16-rounded MFMA weights
        vs_ += b_z[k] * worig;
      }
    }
    us_ += __shfl_xor(us_, 1, 64); us_ += __shfl_xor(us_, 2, 64);
    vs_ += __shfl_xor(vs_, 1, 64); vs_ += __shfl_xor(vs_, 2, 64);
    if (p == 0 && c < 48) { uv_g[c] = us_; uv_g[48 + c] = vs_; }
    return;
  }
  const int tid = threadIdx.x;
  const int w = tid >> 6, l = tid & 63;
  #pragma unroll
  for (int ii = 0; ii < 2; ii++) {
    int row = blockIdx.x * 8 + w * 2 + ii;
    const float* sr = s + (size_t)row * 384;
    float x[6], s1 = 0.f, s2 = 0.f;
    #pragma unroll
    for (int j = 0; j < 6; j++) { x[j] = sr[l + j * 64]; s1 += x[j]; s2 += x[j] * x[j]; }
    #pragma unroll
    for (int m = 1; m < 64; m <<= 1) { s1 += __shfl_xor(s1, m, 64); s2 += __shfl_xor(s2, m, 64); }
    float mean = s1 * (1.f / 384.f);
    float var = s2 * (1.f / 384.f) - mean * mean;
    float rstd = rsqrtf(var + 1e-5f);
    float* dr = sN + (size_t)row * 384;
    #pragma unroll
    for (int j = 0; j < 6; j++) {
      int c = l + j * 64;
      dr[c] = (x[j] - mean) * rstd * g_s[c] + b_s[c];
    }
  }
}

// ---------------------------------------------------------------------------
// K1: FUSED  [blocks 0..1151]  proj = sN(4096x384) @ Wcat(384x1152)
//            [blocks 1152..9343]  z path (LDS-free MFMA)
// ---------------------------------------------------------------------------
__global__ __launch_bounds__(256) void k_zpg(
    const float* __restrict__ sN,
    const float* __restrict__ Wq, const float* __restrict__ Wk,
    const float* __restrict__ Wv, const float* __restrict__ Wqp,
    const float* __restrict__ Wkvp,
    float* __restrict__ proj,
    const float* __restrict__ z,
    const ushort_t* __restrict__ Wt_g, const float* __restrict__ uv_g,
    ushort_t* __restrict__ bbias_t, ushort_t* __restrict__ pzt)
{
  if (blockIdx.x < 1152) {
    // ======================= pgemm half =======================
    __shared__ __align__(16) float sA[16][32];
    __shared__ __align__(16) float sB[16][128];
    const int tid = threadIdx.x;
    const int bid = blockIdx.x;
    const int mt = bid & 127;
    const int nt = bid >> 7;
    const int m0 = mt * 32, n0 = nt * 128;
    const int tm = tid >> 5, tn = tid & 31;

    const float* bsrc[2]; int bstride[2]; int bk[2];
    #pragma unroll
    for (int u = 0; u < 2; u++) {
      int idx = tid + u * 256;
      int k = idx >> 5, n4 = idx & 31;
      int col0 = n0 + n4 * 4;
      const float* p; int st;
      if (col0 < 192)      { p = Wq   + col0;         st = 192; }
      else if (col0 < 384) { p = Wk   + (col0 - 192); st = 192; }
      else if (col0 < 576) { p = Wv   + (col0 - 384); st = 192; }
      else if (col0 < 720) { p = Wqp  + (col0 - 576); st = 144; }
      else                 { p = Wkvp + (col0 - 720); st = 432; }
      bsrc[u] = p; bstride[u] = st; bk[u] = k;
    }
    const int am = tid >> 2, ak4 = tid & 3;

    float acc[4][4];
    #pragma unroll
    for (int i = 0; i < 4; i++)
      #pragma unroll
      for (int j = 0; j < 4; j++) acc[i][j] = 0.f;

    for (int k0 = 0; k0 < 384; k0 += 16) {
      #pragma unroll
      for (int u = 0; u < 2; u++) {
        float4 wv4 = *(const float4*)(bsrc[u] + (size_t)(k0 + bk[u]) * bstride[u]);
        *(float4*)&sB[bk[u]][(tid + u * 256 & 31) * 4] = wv4;
      }
      if (tid < 128) {
        float4 a4 = *(const float4*)(sN + (size_t)(m0 + am) * 384 + k0 + ak4 * 4);
        sA[ak4 * 4 + 0][am] = a4.x;
        sA[ak4 * 4 + 1][am] = a4.y;
        sA[ak4 * 4 + 2][am] = a4.z;
        sA[ak4 * 4 + 3][am] = a4.w;
      }
      __syncthreads();
      #pragma unroll
      for (int kk = 0; kk < 16; kk++) {
        float4 a4 = *(const float4*)&sA[kk][tm * 4];
        float4 b4 = *(const float4*)&sB[kk][tn * 4];
        const float* av = (const float*)&a4;
        const float* bv = (const float*)&b4;
        #pragma unroll
        for (int i = 0; i < 4; i++)
          #pragma unroll
          for (int j = 0; j < 4; j++) acc[i][j] += av[i] * bv[j];
      }
      __syncthreads();
    }
    #pragma unroll
    for (int i = 0; i < 4; i++)
      *(float4*)(proj + (size_t)(m0 + tm * 4 + i) * 1152 + n0 + tn * 4) = *(float4*)&acc[i][0];
  } else {
    // ======================= z half (no LDS, no barriers) =======================
    const int tid = threadIdx.x;
    const int bid = blockIdx.x - 1152;
    const int w = tid >> 6, lane = tid & 63, quad = lane >> 4, r16 = lane & 15;
    const size_t row0 = (size_t)bid * 64;
    const int lrow = w * 16 + r16;                 // this lane's A row (0..63)
    const float* zr = z + (row0 + lrow) * 128;

    // B fragments (loop-invariant), from global Wt tile: rows 44..47 are zeros.
    short8x bf[3][4];
    #pragma unroll
    for (int nt = 0; nt < 3; nt++)
      #pragma unroll
      for (int kk = 0; kk < 4; kk++)
        bf[nt][kk] = *(const short8x*)(Wt_g + (size_t)(nt * 16 + r16) * 128 + kk * 32 + quad * 8);

    // A fragments: 32 raw z floats per lane, cols {quad*8 + kk*32 .. +7}.
    union { short8x v; uint_t u[4]; } afu[4];
    float s1 = 0.f, s2 = 0.f;
    #pragma unroll
    for (int kk = 0; kk < 4; kk++) {
      float4 a = *(const float4*)(zr + kk * 32 + quad * 8);
      float4 b = *(const float4*)(zr + kk * 32 + quad * 8 + 4);
      s1 += a.x + a.y + a.z + a.w + b.x + b.y + b.z + b.w;
      s2 += a.x * a.x + a.y * a.y + a.z * a.z + a.w * a.w
          + b.x * b.x + b.y * b.y + b.z * b.z + b.w * b.w;
      afu[kk].u[0] = pack2(a.x, a.y);
      afu[kk].u[1] = pack2(a.z, a.w);
      afu[kk].u[2] = pack2(b.x, b.y);
      afu[kk].u[3] = pack2(b.z, b.w);
    }
    // Row stats: combine the 4 quad-lanes that share r16 (xor 16, 32).
    s1 += __shfl_xor(s1, 16, 64); s1 += __shfl_xor(s1, 32, 64);
    s2 += __shfl_xor(s2, 16, 64); s2 += __shfl_xor(s2, 32, 64);
    float mean = s1 * (1.f / 128.f);
    float rstd = rsqrtf(s2 * (1.f / 128.f) - mean * mean + 1e-5f);

    floatx4 acc[3] = { {0,0,0,0}, {0,0,0,0}, {0,0,0,0} };
    #pragma unroll
    for (int kk = 0; kk < 4; kk++)
      #pragma unroll
      for (int nt = 0; nt < 3; nt++)
        acc[nt] = __builtin_amdgcn_mfma_f32_16x16x32_bf16(afu[kk].v, bf[nt][kk], acc[nt], 0, 0, 0);

    // C layout: row = quad*4+reg, col = r16.
    float mr[4], rr[4];
    #pragma unroll
    for (int reg = 0; reg < 4; reg++) {
      int src = quad * 4 + reg;
      mr[reg] = __shfl(mean, src, 64);
      rr[reg] = __shfl(rstd, src, 64);
    }

    const int bp = bid >> 6;                 // = b*64+nb
    const int qk0 = (bid & 63) * 64;         // local (q*128+k) base
    const int qloc = qk0 >> 7;               // q index 0..31
    const int kbase = (qk0 & 127) + w * 16 + quad * 4;
    #pragma unroll
    for (int nt = 0; nt < 3; nt++) {
      int c = nt * 16 + r16;
      if (c < 44) {
        float uc = uv_g[c], vc = uv_g[48 + c];
        float vals[4];
        #pragma unroll
        for (int reg = 0; reg < 4; reg++)
          vals[reg] = rr[reg] * acc[nt][reg] - mr[reg] * rr[reg] * uc + vc;
        uint2 pk = make_uint2(pack2(vals[0], vals[1]), pack2(vals[2], vals[3]));
        if (c < 12) {
          size_t el = (((size_t)(bp * 12 + c)) << 12) + qk0 + w * 16 + quad * 4;
          *(uint2*)(bbias_t + el) = pk;
        } else {
          size_t el = (((size_t)((bp * 32 + qloc) * 32 + (c - 12))) << 7) + kbase;
          *(uint2*)(pzt + el) = pk;
        }
      }
    }
  }
}

// ---------------------------------------------------------------------------
// K2: rotations + point norms + scatter to pos* buffers. 8 positions/block.
// ---------------------------------------------------------------------------
__global__ __launch_bounds__(256) void k_rot(
    const float* __restrict__ proj_g,
    const float* __restrict__ trans, const float* __restrict__ rots,
    float* __restrict__ posq, float* __restrict__ posk, float* __restrict__ posv,
    float* __restrict__ posqp, float* __restrict__ poskp, float* __restrict__ posvp,
    float* __restrict__ posqn, float* __restrict__ poskn)
{
  __shared__ __align__(16) float proj[8][1152];
  __shared__ float rt[8][12];
  const int tid = threadIdx.x;
  const int p0 = blockIdx.x * 8;

  for (int e = tid; e < 8 * 288; e += 256)
    ((float4*)&proj[0][0])[e] = ((const float4*)(proj_g + (size_t)p0 * 1152))[e];
  for (int e = tid; e < 8 * 12; e += 256) {
    int i = e / 12, c = e % 12;
    rt[i][c] = (c < 9) ? rots[(size_t)(p0 + i) * 9 + c]
                       : trans[(size_t)(p0 + i) * 3 + (c - 9)];
  }
  __syncthreads();

  for (int e = tid; e < 8 * 192; e += 256) {
    int i = e / 192, p = e % 192;
    float R0 = rt[i][0], R1 = rt[i][1], R2 = rt[i][2];
    float R3 = rt[i][3], R4 = rt[i][4], R5 = rt[i][5];
    float R6 = rt[i][6], R7 = rt[i][7], R8 = rt[i][8];
    float tx = rt[i][9], ty = rt[i][10], tz = rt[i][11];
    size_t pos = p0 + i;
    if (p < 48) {
      int base = 576 + p * 3;
      float v0 = proj[i][base], v1 = proj[i][base + 1], v2 = proj[i][base + 2];
      float o0 = R0 * v0 + R1 * v1 + R2 * v2 + tx;
      float o1 = R3 * v0 + R4 * v1 + R5 * v2 + ty;
      float o2 = R6 * v0 + R7 * v1 + R8 * v2 + tz;
      proj[i][base] = o0; proj[i][base + 1] = o1; proj[i][base + 2] = o2;
      posqp[pos * 144 + p * 3 + 0] = o0;
      posqp[pos * 144 + p * 3 + 1] = o1;
      posqp[pos * 144 + p * 3 + 2] = o2;
    } else {
      int p2 = p - 48;
      int base = 720 + p2 * 3;
      float v0 = proj[i][base], v1 = proj[i][base + 1], v2 = proj[i][base + 2];
      float o0 = R0 * v0 + R1 * v1 + R2 * v2 + tx;
      float o1 = R3 * v0 + R4 * v1 + R5 * v2 + ty;
      float o2 = R6 * v0 + R7 * v1 + R8 * v2 + tz;
      int h = p2 / 12, idx = p2 % 12;
      if (idx < 4) {
        proj[i][base] = o0; proj[i][base + 1] = o1; proj[i][base + 2] = o2;
        poskp[pos * 144 + h * 12 + idx * 3 + 0] = o0;
        poskp[pos * 144 + h * 12 + idx * 3 + 1] = o1;
        poskp[pos * 144 + h * 12 + idx * 3 + 2] = o2;
      } else {
        posvp[pos * 288 + h * 24 + (idx - 4) * 3 + 0] = o0;
        posvp[pos * 288 + h * 24 + (idx - 4) * 3 + 1] = o1;
        posvp[pos * 288 + h * 24 + (idx - 4) * 3 + 2] = o2;
      }
    }
  }
  __syncthreads();

  for (int e = tid; e < 96; e += 256) {
    int i = e / 12, h = e % 12;
    size_t pos = p0 + i;
    float qs = 0.f, ks = 0.f;
    #pragma unroll
    for (int u = 0; u < 12; u++) {
      float a_ = proj[i][576 + h * 12 + u];
      qs += a_ * a_;
      float c_ = proj[i][720 + h * 36 + u];
      ks += c_ * c_;
    }
    posqn[pos * 12 + h] = qs;
    poskn[pos * 12 + h] = ks;
  }
  for (int e = tid; e < 8 * 576; e += 256) {
    int i = e / 576, c = e % 576;
    size_t pos = p0 + i;
    float v = proj[i][c];
    if (c < 192)      posq[pos * 192 + c]         = v;
    else if (c < 384) posk[pos * 192 + (c - 192)] = v;
    else              posv[pos * 192 + (c - 384)] = v;
  }
}

// ---------------------------------------------------------------------------
// K4: attention. 768 blocks = (b, nb, head-pair). 4 waves = (head, q-half).
// ---------------------------------------------------------------------------
__global__ __launch_bounds__(256) void k_attn(
    const float* __restrict__ posq, const float* __restrict__ posk,
    const float* __restrict__ posv, const float* __restrict__ posqp,
    const float* __restrict__ poskp, const float* __restrict__ posvp,
    const float* __restrict__ posqn, const float* __restrict__ poskn,
    const ushort_t* __restrict__ bbias_t,
    const float* __restrict__ s_mask, const int* __restrict__ key_idx,
    const float* __restrict__ trans, const float* __restrict__ rots,
    const float* __restrict__ head_w,
    float* __restrict__ feats, ushort_t* __restrict__ P_ws)
{
  __shared__ __align__(16) ushort_t sK[2 * 128 * 40];  // Kext [hh][k][40] (use 0..31)
  __shared__ __align__(16) ushort_t sV[2 * 48 * 136];  // Vext [hh][c][136] (k 0..127)
  __shared__ __align__(16) ushort_t sQ[2 * 32 * 40];   // Qext [hh][q][40]
  __shared__ __align__(16) ushort_t sP[64 * 136];      // P    [w*16+row][136]
  __shared__ float sOpt[64 * 25];                      // o_pt raw [w*16+row][25]
  __shared__ float rt[32][12];
  __shared__ float kn_l[2][128];
  __shared__ float qn_l[2][32];
  __shared__ float kmask[128];
  __shared__ float qmask[32];
  __shared__ int   kidx[128];
  __shared__ float hwe2[2];

  const int tid = threadIdx.x;
  const int bid = blockIdx.x;
  const int b = bid / 384;
  const int rem = bid % 384;
  const int nb = rem / 6;
  const int hp = rem % 6;
  const int h0 = hp * 2;
  const int rowbase = b * 2048 + nb * 32;

  if (tid < 128) kidx[tid] = key_idx[nb * 128 + tid];
  if (tid < 2) hwe2[tid] = -0.5f * 0.13608276348795434f * log1pf(expf(head_w[h0 + tid]));
  __syncthreads();

  if (tid < 128) kmask[tid] = s_mask[b * 2048 + kidx[tid]];
  if (tid < 32) qmask[tid] = s_mask[rowbase + tid];
  for (int e = tid; e < 384; e += 256) {
    int i = e / 12, c = e % 12;
    rt[i][c] = (c < 9) ? rots[(size_t)(rowbase + i) * 9 + c]
                       : trans[(size_t)(rowbase + i) * 3 + (c - 9)];
  }

  // ---- Kext + kn staging: thread <-> (hh, k) ----
  {
    int hh = tid >> 7, k = tid & 127, h = h0 + hh;
    int gk = b * 2048 + kidx[k];
    kn_l[hh][k] = poskn[(size_t)gk * 12 + h];
    float sq = 0.14433756729740643f;
    float sp = -2.f * hwe2[hh];
    const float* kr = posk + (size_t)gk * 192 + h * 16;
    #pragma unroll
    for (int c4 = 0; c4 < 4; c4++) {
      float4 v4 = *(const float4*)(kr + c4 * 4);
      uint2 pk = make_uint2(pack2(sq * v4.x, sq * v4.y), pack2(sq * v4.z, sq * v4.w));
      *(uint2*)&sK[(hh * 128 + k) * 40 + c4 * 4] = pk;
    }
    const float* kpr = poskp + (size_t)gk * 144 + h * 12;
    #pragma unroll
    for (int c4 = 0; c4 < 3; c4++) {
      float4 v4 = *(const float4*)(kpr + c4 * 4);
      uint2 pk = make_uint2(pack2(sp * v4.x, sp * v4.y), pack2(sp * v4.z, sp * v4.w));
      *(uint2*)&sK[(hh * 128 + k) * 40 + 16 + c4 * 4] = pk;
    }
    *(uint2*)&sK[(hh * 128 + k) * 40 + 28] = make_uint2(0u, 0u);
  }
  // ---- Vext staging (transposed, k-pairs packed) ----
  {
    int hh = tid >> 7, t7 = tid & 127, h = h0 + hh;
    int k2 = t7 >> 1, cg = t7 & 1, kk0 = k2 * 2;
    int ga = b * 2048 + kidx[kk0], gb = b * 2048 + kidx[kk0 + 1];
    if (cg == 0) {
      const float* A_ = posv + (size_t)ga * 192 + h * 16;
      const float* B_ = posv + (size_t)gb * 192 + h * 16;
      #pragma unroll
      for (int c4 = 0; c4 < 4; c4++) {
        float4 a4 = *(const float4*)(A_ + c4 * 4);
        float4 b4 = *(const float4*)(B_ + c4 * 4);
        #pragma unroll
        for (int j = 0; j < 4; j++)
          *(uint_t*)&sV[(hh * 48 + c4 * 4 + j) * 136 + kk0] =
              pack2(((const float*)&a4)[j], ((const float*)&b4)[j]);
      }
    } else {
      const float* A_ = posvp + (size_t)ga * 288 + h * 24;
      const float* B_ = posvp + (size_t)gb * 288 + h * 24;
      #pragma unroll
      for (int c4 = 0; c4 < 6; c4++) {
        float4 a4 = *(const float4*)(A_ + c4 * 4);
        float4 b4 = *(const float4*)(B_ + c4 * 4);
        #pragma unroll
        for (int j = 0; j < 4; j++)
          *(uint_t*)&sV[(hh * 48 + 16 + c4 * 4 + j) * 136 + kk0] =
              pack2(((const float*)&a4)[j], ((const float*)&b4)[j]);
      }
      #pragma unroll
      for (int j = 0; j < 8; j++)
        *(uint_t*)&sV[(hh * 48 + 40 + j) * 136 + kk0] = 0u;
    }
  }
  // ---- Qext + qn staging: thread <-> (hh, q), tid<64 ----
  if (tid < 64) {
    int hh = tid >> 5, q = tid & 31, h = h0 + hh;
    qn_l[hh][q] = posqn[(size_t)(rowbase + q) * 12 + h];
    const float* qr = posq + (size_t)(rowbase + q) * 192 + h * 16;
    #pragma unroll
    for (int c4 = 0; c4 < 4; c4++) {
      float4 v4 = *(const float4*)(qr + c4 * 4);
      uint2 pk = make_uint2(pack2(v4.x, v4.y), pack2(v4.z, v4.w));
      *(uint2*)&sQ[(hh * 32 + q) * 40 + c4 * 4] = pk;
    }
    const float* qpr = posqp + (size_t)(rowbase + q) * 144 + h * 12;
    #pragma unroll
    for (int c4 = 0; c4 < 3; c4++) {
      float4 v4 = *(const float4*)(qpr + c4 * 4);
      uint2 pk = make_uint2(pack2(v4.x, v4.y), pack2(v4.z, v4.w));
      *(uint2*)&sQ[(hh * 32 + q) * 40 + 16 + c4 * 4] = pk;
    }
    *(uint2*)&sQ[(hh * 32 + q) * 40 + 28] = make_uint2(0u, 0u);
  }
  __syncthreads();

  // ---- per-wave compute ----
  const int w = tid >> 6, lane = tid & 63, quad = lane >> 4, r16 = lane & 15;
  const int hh = w >> 1, q0 = (w & 1) * 16;
  const int h = h0 + hh;
  const float hwe = hwe2[hh];

  short8x af = *(const short8x*)&sQ[(hh * 32 + q0 + r16) * 40 + quad * 8];
  floatx4 acc[8];
  #pragma unroll
  for (int nt = 0; nt < 8; nt++) {
    floatx4 z4 = {0.f, 0.f, 0.f, 0.f};
    short8x bf = *(const short8x*)&sK[(hh * 128 + nt * 16 + r16) * 40 + quad * 8];
    acc[nt] = __builtin_amdgcn_mfma_f32_16x16x32_bf16(af, bf, z4, 0, 0, 0);
  }

  const ushort_t* bb = bbias_t + (((size_t)((b * 64 + nb) * 12 + h)) << 12);
  float lg[8][4];
  #pragma unroll
  for (int nt = 0; nt < 8; nt++)
    #pragma unroll
    for (int reg = 0; reg < 4; reg++) {
      int qa = q0 + quad * 4 + reg;
      lg[nt][reg] = b2fu(bb[qa * 128 + nt * 16 + r16]);
    }
  float qnv[4], qmv[4];
  #pragma unroll
  for (int reg = 0; reg < 4; reg++) {
    int qa = q0 + quad * 4 + reg;
    qnv[reg] = qn_l[hh][qa]; qmv[reg] = qmask[qa];
  }
  #pragma unroll
  for (int nt = 0; nt < 8; nt++) {
    int col = nt * 16 + r16;
    float knv = kn_l[hh][col], kmv = kmask[col];
    #pragma unroll
    for (int reg = 0; reg < 4; reg++)
      lg[nt][reg] = acc[nt][reg] + 0.5773502691896258f * lg[nt][reg]
                  + hwe * (qnv[reg] + knv) + 100000.f * (qmv[reg] * kmv - 1.f);
  }
  // softmax over 128 keys per row (in-lane over nt, xor-shuffle over r16)
  float mx[4], sm[4];
  #pragma unroll
  for (int reg = 0; reg < 4; reg++) {
    float m = lg[0][reg];
    #pragma unroll
    for (int nt = 1; nt < 8; nt++) m = fmaxf(m, lg[nt][reg]);
    #pragma unroll
    for (int d = 1; d < 16; d <<= 1) m = fmaxf(m, __shfl_xor(m, d, 64));
    mx[reg] = m; sm[reg] = 0.f;
  }
  #pragma unroll
  for (int nt = 0; nt < 8; nt++)
    #pragma unroll
    for (int reg = 0; reg < 4; reg++) {
      float e = __expf(lg[nt][reg] - mx[reg]);
      lg[nt][reg] = e; sm[reg] += e;
    }
  #pragma unroll
  for (int reg = 0; reg < 4; reg++) {
    float s = sm[reg];
    #pragma unroll
    for (int d = 1; d < 16; d <<= 1) s += __shfl_xor(s, d, 64);
    sm[reg] = 1.f / s;
  }
  // P -> LDS (wave-private)
  #pragma unroll
  for (int nt = 0; nt < 8; nt++)
    #pragma unroll
    for (int reg = 0; reg < 4; reg++) {
      int row = quad * 4 + reg;
      sP[(w * 16 + row) * 136 + nt * 16 + r16] = f2bu(lg[nt][reg] * sm[reg]);
    }
  // PV
  short8x afp[4];
  #pragma unroll
  for (int kk = 0; kk < 4; kk++)
    afp[kk] = *(const short8x*)&sP[(w * 16 + r16) * 136 + kk * 32 + quad * 8];
  floatx4 o0 = {0.f,0.f,0.f,0.f}, o1 = {0.f,0.f,0.f,0.f}, o2 = {0.f,0.f,0.f,0.f};
  #pragma unroll
  for (int kk = 0; kk < 4; kk++) {
    short8x bv0 = *(const short8x*)&sV[(hh * 48 +  0 + r16) * 136 + kk * 32 + quad * 8];
    short8x bv1 = *(const short8x*)&sV[(hh * 48 + 16 + r16) * 136 + kk * 32 + quad * 8];
    short8x bv2 = *(const short8x*)&sV[(hh * 48 + 32 + r16) * 136 + kk * 32 + quad * 8];
    o0 = __builtin_amdgcn_mfma_f32_16x16x32_bf16(afp[kk], bv0, o0, 0, 0, 0);
    o1 = __builtin_amdgcn_mfma_f32_16x16x32_bf16(afp[kk], bv1, o1, 0, 0, 0);
    o2 = __builtin_amdgcn_mfma_f32_16x16x32_bf16(afp[kk], bv2, o2, 0, 0, 0);
  }
  // o epilogue (cols 0..15 = c)
  #pragma unroll
  for (int reg = 0; reg < 4; reg++) {
    int qa = q0 + quad * 4 + reg;
    feats[(size_t)(rowbase + qa) * 960 + h * 16 + r16] = o0[reg];
  }
  // o_pt raw -> LDS
  #pragma unroll
  for (int reg = 0; reg < 4; reg++) {
    int row = quad * 4 + reg;
    sOpt[(w * 16 + row) * 25 + r16] = o1[reg];
    if (r16 < 8) sOpt[(w * 16 + row) * 25 + 16 + r16] = o2[reg];
  }
  // rotation + norm epilogue (same wave; LDS deps via waitcnt)
  for (int e2 = lane; e2 < 128; e2 += 64) {
    int ql = e2 >> 3, v = e2 & 7;
    int qa = q0 + ql;
    float u0 = sOpt[(w * 16 + ql) * 25 + v * 3 + 0] - rt[qa][9];
    float u1 = sOpt[(w * 16 + ql) * 25 + v * 3 + 1] - rt[qa][10];
    float u2 = sOpt[(w * 16 + ql) * 25 + v * 3 + 2] - rt[qa][11];
    float w0 = rt[qa][0] * u0 + rt[qa][3] * u1 + rt[qa][6] * u2;
    float w1 = rt[qa][1] * u0 + rt[qa][4] * u1 + rt[qa][7] * u2;
    float w2 = rt[qa][2] * u0 + rt[qa][5] * u1 + rt[qa][8] * u2;
    size_t fb = (size_t)(rowbase + qa) * 960;
    feats[fb + 192 + h * 24 + v * 3 + 0] = w0;
    feats[fb + 192 + h * 24 + v * 3 + 1] = w1;
    feats[fb + 192 + h * 24 + v * 3 + 2] = w2;
    feats[fb + 480 + h * 8 + v] = sqrtf(w0 * w0 + w1 * w1 + w2 * w2 + 1e-8f);
  }
  // P -> global (for k_opair), coalesced uint stores
  {
    uint_t* Pg = (uint_t*)P_ws;
    size_t pb2 = (((size_t)((b * 64 + nb) * 12 + h)) << 12) >> 1;  // uint index base
    #pragma unroll
    for (int ql = 0; ql < 16; ql++) {
      uint_t pv = *(const uint_t*)&sP[(w * 16 + ql) * 136 + 2 * lane];
      Pg[pb2 + (size_t)(q0 + ql) * 64 + lane] = pv;
    }
  }
}

// ---------------------------------------------------------------------------
// K5: o_pair. 1024 blocks = (b, nb, q-quad). wave <-> q.
// ---------------------------------------------------------------------------
__global__ __launch_bounds__(256) void k_opair(
    const ushort_t* __restrict__ P_ws, const ushort_t* __restrict__ pzt,
    float* __restrict__ feats)
{
  __shared__ __align__(16) ushort_t pzl[4 * 32 * 136];
  const int tid = threadIdx.x;
  const int w = tid >> 6, lane = tid & 63, quad = lane >> 4, r16 = lane & 15;
  const int bid = blockIdx.x;
  const int b = bid >> 9, rem = bid & 511, nb = rem >> 3, qg = rem & 7;
  const int q = qg * 4 + w;
  const int rowbase = b * 2048 + nb * 32;

  // stage this wave's pz tile (transposed layout already): 32 c-rows x 128 k
  const uint_t* src = (const uint_t*)pzt + ((((size_t)((b * 64 + nb) * 32 + q)) << 12) >> 1);
  #pragma unroll
  for (int c = 0; c < 32; c++) {
    uint_t v = src[c * 64 + lane];
    *(uint_t*)&pzl[(w * 32 + c) * 136 + 2 * lane] = v;
  }
  // A-frags from global P
  const ushort_t* Pp = P_ws + ((size_t)(b * 64 + nb) * 12) * 4096
                            + (size_t)r16 * 4096 + (size_t)q * 128;
  short8x af[4];
  #pragma unroll
  for (int kk = 0; kk < 4; kk++)
    af[kk] = *(const short8x*)(Pp + kk * 32 + quad * 8);

  floatx4 acc[2] = { {0.f,0.f,0.f,0.f}, {0.f,0.f,0.f,0.f} };
  #pragma unroll
  for (int kk = 0; kk < 4; kk++) {
    #pragma unroll
    for (int nt = 0; nt < 2; nt++) {
      short8x bf = *(const short8x*)&pzl[(w * 32 + nt * 16 + r16) * 136 + kk * 32 + quad * 8];
      acc[nt] = __builtin_amdgcn_mfma_f32_16x16x32_bf16(af[kk], bf, acc[nt], 0, 0, 0);
    }
  }
  #pragma unroll
  for (int nt = 0; nt < 2; nt++)
    #pragma unroll
    for (int reg = 0; reg < 4; reg++) {
      int hrow = quad * 4 + reg;
      if (hrow < 12)
        feats[(size_t)(rowbase + q) * 960 + 576 + hrow * 32 + nt * 16 + r16] = acc[nt][reg];
    }
}

// ---------------------------------------------------------------------------
// K6: out = feats(4096x960) @ Wout(960x384) via 3-term bf16 MFMA.
// 256 blocks x 512 threads; 16 rows/block; wave owns 48 output cols.
// A (feats rows) staged in LDS as hi/lo bf16; B from precomputed WoT_hi/lo.
// out = Ahi*Bhi + Alo*Bhi + Ahi*Blo  (dropped Alo*Blo ~ 2^-18 rel).
// ---------------------------------------------------------------------------
__global__ __launch_bounds__(512) void k_out(
    const float* __restrict__ feats,
    const ushort_t* __restrict__ woT_hi, const ushort_t* __restrict__ woT_lo,
    float* __restrict__ out)
{
  __shared__ __align__(16) ushort_t hiA[16 * 968];   // stride 968: 2-way banks (free)
  __shared__ __align__(16) ushort_t loA[16 * 968];
  const int tid = threadIdx.x;
  const int p0 = blockIdx.x * 16;

  for (int e = tid; e < 16 * 240; e += 512) {
    int i = e / 240, c4 = e % 240;
    float4 v = ((const float4*)&feats[(size_t)(p0 + i) * 960])[c4];
    ushort_t h0 = f2bu(v.x), h1 = f2bu(v.y), h2 = f2bu(v.z), h3 = f2bu(v.w);
    uint2 hp = make_uint2((uint_t)h0 | ((uint_t)h1 << 16), (uint_t)h2 | ((uint_t)h3 << 16));
    uint2 lp = make_uint2(pack2(v.x - b2fu(h0), v.y - b2fu(h1)),
                          pack2(v.z - b2fu(h2), v.w - b2fu(h3)));
    *(uint2*)&hiA[i * 968 + c4 * 4] = hp;
    *(uint2*)&loA[i * 968 + c4 * 4] = lp;
  }
  __syncthreads();

  const int wv = tid >> 6, lane = tid & 63, quad = lane >> 4, r16 = lane & 15;
  const int n0 = wv * 48;
  floatx4 acc[3] = { {0.f,0.f,0.f,0.f}, {0.f,0.f,0.f,0.f}, {0.f,0.f,0.f,0.f} };

  #pragma unroll 2
  for (int ks = 0; ks < 30; ks++) {
    int k0 = ks * 32;
    short8x ah = *(const short8x*)&hiA[r16 * 968 + k0 + quad * 8];
    short8x al = *(const short8x*)&loA[r16 * 968 + k0 + quad * 8];
    #pragma unroll
    for (int nt = 0; nt < 3; nt++) {
      size_t bo = (size_t)(n0 + nt * 16 + r16) * 960 + k0 + quad * 8;
      short8x bh = *(const short8x*)(woT_hi + bo);
      short8x bl = *(const short8x*)(woT_lo + bo);
      acc[nt] = __builtin_amdgcn_mfma_f32_16x16x32_bf16(ah, bh, acc[nt], 0, 0, 0);
      acc[nt] = __builtin_amdgcn_mfma_f32_16x16x32_bf16(al, bh, acc[nt], 0, 0, 0);
      acc[nt] = __builtin_amdgcn_mfma_f32_16x16x32_bf16(ah, bl, acc[nt], 0, 0, 0);
    }
  }
  #pragma unroll
  for (int nt = 0; nt < 3; nt++)
    #pragma unroll
    for (int reg = 0; reg < 4; reg++) {
      int row = quad * 4 + reg;
      out[(size_t)(p0 + row) * 384 + n0 + nt * 16 + r16] = acc[nt][reg];
    }
}

// ---------------------------------------------------------------------------
extern "C" void kernel_launch(void* const* d_in, const int* in_sizes, int n_in,
                              void* d_out, int out_size, void* d_ws, size_t ws_size,
                              hipStream_t stream) {
  const float* s      = (const float*)d_in[0];
  const float* z      = (const float*)d_in[1];
  const float* trans  = (const float*)d_in[2];
  const float* rots   = (const float*)d_in[3];
  const float* s_mask = (const float*)d_in[4];
  const int*   key_idx= (const int*)d_in[5];
  const float* ln_s_g = (const float*)d_in[6];
  const float* ln_s_b = (const float*)d_in[7];
  const float* ln_z_g = (const float*)d_in[8];
  const float* ln_z_b = (const float*)d_in[9];
  const float* Wq     = (const float*)d_in[10];
  const float* Wk     = (const float*)d_in[11];
  const float* Wv     = (const float*)d_in[12];
  const float* Wqp    = (const float*)d_in[13];
  const float* Wkvp   = (const float*)d_in[14];
  const float* Wb     = (const float*)d_in[15];
  const float* Wdz    = (const float*)d_in[16];
  const float* head_w = (const float*)d_in[17];
  const float* Wout   = (const float*)d_in[18];

  char* wsb = (char*)d_ws;
  float* posq  = (float*)(wsb + 0);          // 2*2048*192 f32
  float* posk  = (float*)(wsb + 3145728);
  float* posv  = (float*)(wsb + 6291456);
  float* posqp = (float*)(wsb + 9437184);    // 2*2048*144
  float* poskp = (float*)(wsb + 11796480);
  float* posvp = (float*)(wsb + 14155776);   // 2*2048*288
  float* posqn = (float*)(wsb + 18874368);   // 2*2048*12
  float* poskn = (float*)(wsb + 19070976);
  float* feats = (float*)(wsb + 19267584);   // 4096*960 f32 (15.7 MB)
  float* sN    = (float*)(wsb + 19267584);   // shares feats (dead before k_attn)
  float* proj  = (float*)(wsb + 34996224);   // 18,874,368 B  -> ends 53,870,592
  ushort_t* bbias_t = (ushort_t*)(wsb + 53870592);   // 12,582,912 B
  ushort_t* pzt     = (ushort_t*)(wsb + 66453504);   // 33,554,432 B
  ushort_t* P_ws    = (ushort_t*)(wsb + 100007936);  // 12,582,912 B
  ushort_t* Wt_ws   = (ushort_t*)(wsb + 112590848);  // 12,288 B
  float*    uv_ws   = (float*)(wsb + 112603136);     // 384 B -> ends 112,603,520
  ushort_t* woT_hi  = (ushort_t*)(wsb + 112603520);  // 737,280 B
  ushort_t* woT_lo  = (ushort_t*)(wsb + 113340800);  // 737,280 B -> ends 114,078,080

  // 512 LN blocks + 1 z-weight prep + 96 Wout transpose/split prep
  k_ln<<<609, 256, 0, stream>>>(s, ln_s_g, ln_s_b, sN,
                                ln_z_g, ln_z_b, Wb, Wdz, Wt_ws, uv_ws,
                                Wout, woT_hi, woT_lo);
  // fused: blocks 0..1151 = pgemm, 1152..9343 = z path (independent halves)
  k_zpg<<<9344, 256, 0, stream>>>(sN, Wq, Wk, Wv, Wqp, Wkvp, proj,
                                  z, Wt_ws, uv_ws, bbias_t, pzt);
  k_rot<<<512, 256, 0, stream>>>(proj, trans, rots,
                                 posq, posk, posv, posqp, poskp, posvp, posqn, poskn);
  k_attn<<<768, 256, 0, stream>>>(posq, posk, posv, posqp, poskp, posvp, posqn, poskn,
                                  bbias_t, s_mask, key_idx, trans, rots, head_w,
                                  feats, P_ws);
  k_opair<<<1024, 256, 0, stream>>>(P_ws, pzt, feats);
  k_out<<<256, 512, 0, stream>>>(feats, woT_hi, woT_lo, (float*)d_out);
}